// Round 8
// baseline (178.953 us; speedup 1.0000x reference)
//
#include <hip/hip_runtime.h>
#include <hip/hip_bf16.h>
#include <hip/hip_cooperative_groups.h>

namespace cg = cooperative_groups;

#define NE 800000   // edges
#define NN 50000    // nodes
#define TPW 4       // tiles/wave for fallback edge kernel
#define NTILES (NE / 16)       // 50000
#define NODE_TILES (NN / 16)   // 3125
#define NUNITS (NTILES / 2)    // 25000 2-tile units for the fused kernel
#define W1LD 136

typedef __attribute__((ext_vector_type(8))) short        s16x8;
typedef __attribute__((ext_vector_type(8))) __bf16       bf16x8;
typedef __attribute__((ext_vector_type(4))) float        f32x4;
typedef __attribute__((ext_vector_type(2))) float        f32x2;
typedef __attribute__((ext_vector_type(4))) unsigned int u32x4;
typedef __attribute__((ext_vector_type(2))) unsigned int u32x2;

// ws layout (unsigned short elems):
//   [0)      w1t region (fallback weight packs)
//   [10240)  w2t [32][64]
//   [12288)  w3t [16][32]
//   [16384)  At [NN][64] bf16 (nf @ W1[0:64] + b1); then Bt [NN][64]
#define TAB_OFF 16384
#define WS_TAB ((size_t)(TAB_OFF + 2ull * NN * 64) * 2)
#define WS_NFB ((size_t)(TAB_OFF + 1ull * NN * 64) * 2)

__device__ __forceinline__ unsigned short f2bf_bits(float f) {
    __bf16 b = (__bf16)f;
    return __builtin_bit_cast(unsigned short, b);
}

__device__ __forceinline__ unsigned int pkbf(float a, float b) {
    return (unsigned int)f2bf_bits(a) | ((unsigned int)f2bf_bits(b) << 16);
}

__device__ __forceinline__ s16x8 cvt8(f32x4 a, f32x4 b) {
    bf16x8 r;
    r[0] = (__bf16)a[0]; r[1] = (__bf16)a[1]; r[2] = (__bf16)a[2]; r[3] = (__bf16)a[3];
    r[4] = (__bf16)b[0]; r[5] = (__bf16)b[1]; r[6] = (__bf16)b[2]; r[7] = (__bf16)b[3];
    return __builtin_bit_cast(s16x8, r);
}

__device__ __forceinline__ void gatherT(const unsigned short* At, const unsigned short* Bt,
                                        int si, int di, int lg, s16x8 g[4]) {
    const unsigned short* pa = At + (size_t)si * 64 + lg * 8;
    const unsigned short* pb = Bt + (size_t)di * 64 + lg * 8;
    g[0] = *reinterpret_cast<const s16x8*>(pa);
    g[1] = *reinterpret_cast<const s16x8*>(pa + 32);
    g[2] = *reinterpret_cast<const s16x8*>(pb);
    g[3] = *reinterpret_cast<const s16x8*>(pb + 32);
}

// shared per-tile compute: h1(fused add) -> L2 MFMA -> L3 MFMA -> store
__device__ __forceinline__ void compute_tile(
    int tile, const s16x8 cur[4], f32x2 s2,
    const f32x2 c0p[2][4], const f32x2 c1p[2][4],
    const s16x8 w2f[2][2], s16x8 w3f,
    const f32x4 b2v[2], f32x4 b3v,
    unsigned short* h2w, int lg, int lr, float* __restrict__ out) {

    const f32x2 sp0v = {s2[0], s2[0]}, sp1v = {s2[1], s2[1]};

    s16x8 bfr[2];
    #pragma unroll
    for (int jb = 0; jb < 2; ++jb) {
        u32x4 au = __builtin_bit_cast(u32x4, cur[jb]);
        u32x4 bu = __builtin_bit_cast(u32x4, cur[2 + jb]);
        u32x4 pk4;
        #pragma unroll
        for (int q = 0; q < 4; ++q) {
            f32x2 av = {__builtin_bit_cast(float, au[q] << 16),
                        __builtin_bit_cast(float, au[q] & 0xFFFF0000u)};
            f32x2 bv = {__builtin_bit_cast(float, bu[q] << 16),
                        __builtin_bit_cast(float, bu[q] & 0xFFFF0000u)};
            f32x2 h = av + bv;
            h = sp1v * c1p[jb][q] + h;
            h = sp0v * c0p[jb][q] + h;
            pk4[q] = pkbf(fmaxf(h[0], 0.f), fmaxf(h[1], 0.f));
        }
        bfr[jb] = __builtin_bit_cast(s16x8, pk4);
    }

    f32x4 acc2[2];
    #pragma unroll
    for (int c = 0; c < 2; ++c) acc2[c] = (f32x4){0, 0, 0, 0};
    #pragma unroll
    for (int s = 0; s < 2; ++s)
        #pragma unroll
        for (int c = 0; c < 2; ++c)
            acc2[c] = __builtin_amdgcn_mfma_f32_16x16x32_bf16(w2f[s][c], bfr[s], acc2[c], 0, 0, 0);

    #pragma unroll
    for (int c = 0; c < 2; ++c) {
        u32x2 p;
        p[0] = pkbf(fmaxf(acc2[c][0] + b2v[c][0], 0.f), fmaxf(acc2[c][1] + b2v[c][1], 0.f));
        p[1] = pkbf(fmaxf(acc2[c][2] + b2v[c][2], 0.f), fmaxf(acc2[c][3] + b2v[c][3], 0.f));
        *reinterpret_cast<u32x2*>(h2w + c * 16 + lg * 4) = p;
    }

    s16x8 bf3 = *reinterpret_cast<const s16x8*>(h2w + lg * 8);
    f32x4 acc3 = (f32x4){0, 0, 0, 0};
    acc3 = __builtin_amdgcn_mfma_f32_16x16x32_bf16(w3f, bf3, acc3, 0, 0, 0);

    f32x4 o;
    #pragma unroll
    for (int r = 0; r < 4; ++r) o[r] = acc3[r] + b3v[r];
    __builtin_nontemporal_store(o,
        reinterpret_cast<f32x4*>(out + (long)(tile * 16 + lr) * 16 + lg * 4));
}

__device__ __forceinline__ void load_unit_idx(const int* __restrict__ ei,
                                              const float* __restrict__ sp, int u, int lr,
                                              int si[2], int di[2], f32x2 spv[2]) {
    #pragma unroll
    for (int v = 0; v < 2; ++v) {
        const size_t e = (size_t)(u * 2 + v) * 16 + lr;
        si[v] = ei[e];
        di[v] = ei[NE + e];
        spv[v] = *reinterpret_cast<const f32x2*>(sp + 2 * e);
    }
}

// ================= fused cooperative kernel: tables + grid.sync + edges =================
__global__ __launch_bounds__(256, 4) void fused_all(
    const float* __restrict__ nf, const int* __restrict__ ei,
    const float* __restrict__ sp, const float* __restrict__ W1,
    const float* __restrict__ b1, const float* __restrict__ W2,
    const float* __restrict__ b2, const float* __restrict__ W3,
    const float* __restrict__ b3, unsigned short* __restrict__ tab,
    float* __restrict__ out) {

    unsigned short* At = tab;
    unsigned short* Bt = tab + (size_t)NN * 64;

    __shared__ unsigned short h2s[4 * 16 * 40];   // per-wave regions, 5 KiB

    const int tid = threadIdx.x, wid = tid >> 6, lane = tid & 63;
    const int lr = lane & 15, lg = lane >> 4;
    const int gwave  = blockIdx.x * 4 + wid;
    const int nwaves = gridDim.x * 4;

    // ---------- phase A: node tables (1 tile per wave pass) ----------
    if (gwave < NODE_TILES) {
        s16x8 w1f[4][4];   // W1^T[j=c*16+lr][k=s*32+lg*8+b], direct strided f32 loads
        #pragma unroll
        for (int s = 0; s < 4; ++s)
            #pragma unroll
            for (int c = 0; c < 4; ++c) {
                bf16x8 w;
                #pragma unroll
                for (int b = 0; b < 8; ++b)
                    w[b] = (__bf16)W1[(s * 32 + lg * 8 + b) * 64 + c * 16 + lr];
                w1f[s][c] = __builtin_bit_cast(s16x8, w);
            }
        f32x4 b1q[4];
        #pragma unroll
        for (int c = 0; c < 4; ++c)
            b1q[c] = *reinterpret_cast<const f32x4*>(b1 + c * 16 + lg * 4);

        for (int tile = gwave; tile < NODE_TILES; tile += nwaves) {
            const int row = tile * 16 + lr;
            const float* p = nf + (long)row * 64;
            s16x8 nfr[2];
            #pragma unroll
            for (int s = 0; s < 2; ++s) {
                f32x4 a = *reinterpret_cast<const f32x4*>(p + s * 32 + lg * 8);
                f32x4 b = *reinterpret_cast<const f32x4*>(p + s * 32 + lg * 8 + 4);
                nfr[s] = cvt8(a, b);
            }
            f32x4 a4[4], b4[4];
            #pragma unroll
            for (int c = 0; c < 4; ++c) { a4[c] = (f32x4){0,0,0,0}; b4[c] = (f32x4){0,0,0,0}; }
            #pragma unroll
            for (int s = 0; s < 2; ++s)
                #pragma unroll
                for (int c = 0; c < 4; ++c) {
                    a4[c] = __builtin_amdgcn_mfma_f32_16x16x32_bf16(w1f[s][c],     nfr[s], a4[c], 0, 0, 0);
                    b4[c] = __builtin_amdgcn_mfma_f32_16x16x32_bf16(w1f[s + 2][c], nfr[s], b4[c], 0, 0, 0);
                }
            #pragma unroll
            for (int c = 0; c < 4; ++c) {
                u32x2 pa, pb;
                pa[0] = pkbf(a4[c][0] + b1q[c][0], a4[c][1] + b1q[c][1]);
                pa[1] = pkbf(a4[c][2] + b1q[c][2], a4[c][3] + b1q[c][3]);
                pb[0] = pkbf(b4[c][0], b4[c][1]);
                pb[1] = pkbf(b4[c][2], b4[c][3]);
                *reinterpret_cast<u32x2*>(At + (long)row * 64 + c * 16 + lg * 4) = pa;
                *reinterpret_cast<u32x2*>(Bt + (long)row * 64 + c * 16 + lg * 4) = pb;
            }
        }
    }

    __threadfence();
    cg::this_grid().sync();

    // ---------- phase B: persistent edge loop (weights live across all units) ----------
    s16x8 w2f[2][2];
    #pragma unroll
    for (int s = 0; s < 2; ++s)
        #pragma unroll
        for (int c = 0; c < 2; ++c) {
            bf16x8 w;
            #pragma unroll
            for (int b = 0; b < 8; ++b)
                w[b] = (__bf16)W2[(s * 32 + lg * 8 + b) * 32 + c * 16 + lr];
            w2f[s][c] = __builtin_bit_cast(s16x8, w);
        }
    s16x8 w3f;
    {
        bf16x8 w;
        #pragma unroll
        for (int b = 0; b < 8; ++b) w[b] = (__bf16)W3[(lg * 8 + b) * 16 + lr];
        w3f = __builtin_bit_cast(s16x8, w);
    }

    f32x4 b2v[2];
    #pragma unroll
    for (int c = 0; c < 2; ++c) b2v[c] = *reinterpret_cast<const f32x4*>(b2 + c * 16 + lg * 4);
    const f32x4 b3v = *reinterpret_cast<const f32x4*>(b3 + lg * 4);

    f32x2 c0p[2][4], c1p[2][4];
    #pragma unroll
    for (int jb = 0; jb < 2; ++jb) {
        const int j0 = jb * 32 + lg * 8;
        f32x4 x0 = *reinterpret_cast<const f32x4*>(W1 + 128 * 64 + j0);
        f32x4 x1 = *reinterpret_cast<const f32x4*>(W1 + 128 * 64 + j0 + 4);
        f32x4 y0 = *reinterpret_cast<const f32x4*>(W1 + 129 * 64 + j0);
        f32x4 y1 = *reinterpret_cast<const f32x4*>(W1 + 129 * 64 + j0 + 4);
        c0p[jb][0] = (f32x2){x0[0], x0[1]}; c0p[jb][1] = (f32x2){x0[2], x0[3]};
        c0p[jb][2] = (f32x2){x1[0], x1[1]}; c0p[jb][3] = (f32x2){x1[2], x1[3]};
        c1p[jb][0] = (f32x2){y0[0], y0[1]}; c1p[jb][1] = (f32x2){y0[2], y0[3]};
        c1p[jb][2] = (f32x2){y1[0], y1[1]}; c1p[jb][3] = (f32x2){y1[2], y1[3]};
    }

    unsigned short* h2w = h2s + wid * (16 * 40) + lr * 40;

    int u = gwave;
    if (u < NUNITS) {
        int si[2], di[2];
        f32x2 spv[2];
        load_unit_idx(ei, sp, u, lr, si, di, spv);
        for (;;) {
            const int un = u + nwaves;
            const bool more = (un < NUNITS);
            s16x8 cur[4], nxt[4];
            gatherT(At, Bt, si[0], di[0], lg, cur);
            int si2[2], di2[2];
            f32x2 spv2[2];
            if (more) load_unit_idx(ei, sp, un, lr, si2, di2, spv2);
            gatherT(At, Bt, si[1], di[1], lg, nxt);
            compute_tile(u * 2,     cur, spv[0], c0p, c1p, w2f, w3f, b2v, b3v, h2w, lg, lr, out);
            compute_tile(u * 2 + 1, nxt, spv[1], c0p, c1p, w2f, w3f, b2v, b3v, h2w, lg, lr, out);
            if (!more) break;
            #pragma unroll
            for (int v = 0; v < 2; ++v) { si[v] = si2[v]; di[v] = di2[v]; spv[v] = spv2[v]; }
            u = un;
        }
    }
}

// ================= fallback: proven R6 two-kernel tab path =================
__global__ __launch_bounds__(256) void node_prep_all(
    const float* __restrict__ nf, const float* __restrict__ W1,
    const float* __restrict__ b1, const float* __restrict__ W2,
    const float* __restrict__ W3, unsigned short* __restrict__ ws) {
    unsigned short* w2t = ws + 10240;
    unsigned short* w3t = ws + 12288;
    unsigned short* At  = ws + TAB_OFF;
    unsigned short* Bt  = At + (size_t)NN * 64;

    __shared__ unsigned short w1l[64 * W1LD];

    const int tid = threadIdx.x, wid = tid >> 6, lane = tid & 63;
    const int lr = lane & 15, lg = lane >> 4;

    for (int i = tid; i < 128 * 64; i += 256) {
        const int k = i >> 6, j = i & 63;
        w1l[j * W1LD + k] = f2bf_bits(W1[i]);
    }
    __syncthreads();

    if (blockIdx.x == 0) {
        for (int i = tid; i < 32 * 64; i += 256) {
            int j = i / 64, k = i % 64;
            w2t[i] = f2bf_bits(W2[k * 32 + j]);
        }
        for (int i = tid; i < 16 * 32; i += 256) {
            int j = i / 32, k = i % 32;
            w3t[i] = f2bf_bits(W3[k * 16 + j]);
        }
    }

    s16x8 w1f[4][4];
    #pragma unroll
    for (int s = 0; s < 4; ++s)
        #pragma unroll
        for (int c = 0; c < 4; ++c)
            w1f[s][c] = *reinterpret_cast<const s16x8*>(
                &w1l[(c * 16 + lr) * W1LD + s * 32 + lg * 8]);

    f32x4 b1q[4];
    #pragma unroll
    for (int c = 0; c < 4; ++c)
        b1q[c] = *reinterpret_cast<const f32x4*>(b1 + c * 16 + lg * 4);

    const int tile = blockIdx.x * 4 + wid;
    if (tile >= NODE_TILES) return;

    const int row = tile * 16 + lr;
    const float* p = nf + (long)row * 64;
    s16x8 nfr[2];
    #pragma unroll
    for (int s = 0; s < 2; ++s) {
        f32x4 a = *reinterpret_cast<const f32x4*>(p + s * 32 + lg * 8);
        f32x4 b = *reinterpret_cast<const f32x4*>(p + s * 32 + lg * 8 + 4);
        nfr[s] = cvt8(a, b);
    }
    f32x4 a4[4], b4[4];
    #pragma unroll
    for (int c = 0; c < 4; ++c) { a4[c] = (f32x4){0,0,0,0}; b4[c] = (f32x4){0,0,0,0}; }
    #pragma unroll
    for (int s = 0; s < 2; ++s)
        #pragma unroll
        for (int c = 0; c < 4; ++c) {
            a4[c] = __builtin_amdgcn_mfma_f32_16x16x32_bf16(w1f[s][c],     nfr[s], a4[c], 0, 0, 0);
            b4[c] = __builtin_amdgcn_mfma_f32_16x16x32_bf16(w1f[s + 2][c], nfr[s], b4[c], 0, 0, 0);
        }
    #pragma unroll
    for (int c = 0; c < 4; ++c) {
        u32x2 pa, pb;
        pa[0] = pkbf(a4[c][0] + b1q[c][0], a4[c][1] + b1q[c][1]);
        pa[1] = pkbf(a4[c][2] + b1q[c][2], a4[c][3] + b1q[c][3]);
        pb[0] = pkbf(b4[c][0], b4[c][1]);
        pb[1] = pkbf(b4[c][2], b4[c][3]);
        *reinterpret_cast<u32x2*>(At + (long)row * 64 + c * 16 + lg * 4) = pa;
        *reinterpret_cast<u32x2*>(Bt + (long)row * 64 + c * 16 + lg * 4) = pb;
    }
}

__global__ __launch_bounds__(256) void edge_mlp_tab(
    const int* __restrict__ ei, const float* __restrict__ sp,
    const float* __restrict__ W1, const float* __restrict__ b2,
    const float* __restrict__ b3, const unsigned short* __restrict__ wsw,
    float* __restrict__ out) {

    const unsigned short* w2t = wsw + 10240;
    const unsigned short* w3t = wsw + 12288;
    const unsigned short* At  = wsw + TAB_OFF;
    const unsigned short* Bt  = At + (size_t)NN * 64;

    __shared__ unsigned short h2s[4 * 16 * 40];

    const int tid = threadIdx.x, wid = tid >> 6, lane = tid & 63;
    const int lr = lane & 15, lg = lane >> 4;

    const int tile0 = (blockIdx.x * 4 + wid) * TPW;

    s16x8 w2f[2][2], w3f;
    #pragma unroll
    for (int s = 0; s < 2; ++s)
        #pragma unroll
        for (int c = 0; c < 2; ++c)
            w2f[s][c] = *reinterpret_cast<const s16x8*>(w2t + (c * 16 + lr) * 64 + s * 32 + lg * 8);
    w3f = *reinterpret_cast<const s16x8*>(w3t + lr * 32 + lg * 8);

    f32x4 b2v[2];
    #pragma unroll
    for (int c = 0; c < 2; ++c) b2v[c] = *reinterpret_cast<const f32x4*>(b2 + c * 16 + lg * 4);
    const f32x4 b3v = *reinterpret_cast<const f32x4*>(b3 + lg * 4);

    f32x2 c0p[2][4], c1p[2][4];
    #pragma unroll
    for (int jb = 0; jb < 2; ++jb) {
        const int j0 = jb * 32 + lg * 8;
        f32x4 x0 = *reinterpret_cast<const f32x4*>(W1 + 128 * 64 + j0);
        f32x4 x1 = *reinterpret_cast<const f32x4*>(W1 + 128 * 64 + j0 + 4);
        f32x4 y0 = *reinterpret_cast<const f32x4*>(W1 + 129 * 64 + j0);
        f32x4 y1 = *reinterpret_cast<const f32x4*>(W1 + 129 * 64 + j0 + 4);
        c0p[jb][0] = (f32x2){x0[0], x0[1]}; c0p[jb][1] = (f32x2){x0[2], x0[3]};
        c0p[jb][2] = (f32x2){x1[0], x1[1]}; c0p[jb][3] = (f32x2){x1[2], x1[3]};
        c1p[jb][0] = (f32x2){y0[0], y0[1]}; c1p[jb][1] = (f32x2){y0[2], y0[3]};
        c1p[jb][2] = (f32x2){y1[0], y1[1]}; c1p[jb][3] = (f32x2){y1[2], y1[3]};
    }

    unsigned short* h2w = h2s + wid * (16 * 40) + lr * 40;

    int si[TPW], di[TPW];
    f32x2 spv[TPW];
    #pragma unroll
    for (int t = 0; t < TPW; ++t) {
        const size_t e = (size_t)(tile0 + t) * 16 + lr;
        si[t] = ei[e];
        di[t] = ei[NE + e];
        spv[t] = *reinterpret_cast<const f32x2*>(sp + 2 * e);
    }

    s16x8 cur[4], nxt[4];
    gatherT(At, Bt, si[0], di[0], lg, cur);

    #pragma unroll
    for (int tt = 0; tt < TPW; ++tt) {
        if (tt + 1 < TPW)
            gatherT(At, Bt, si[tt + 1], di[tt + 1], lg, nxt);
        compute_tile(tile0 + tt, cur, spv[tt], c0p, c1p, w2f, w3f,
                     b2v, b3v, h2w, lg, lr, out);
        #pragma unroll
        for (int s = 0; s < 4; ++s) cur[s] = nxt[s];
    }
}

// ---------------- small-ws fallback (R2 kernel, proven) ----------------
__global__ void prep(const float* __restrict__ W1, const float* __restrict__ W2,
                     const float* __restrict__ W3, const float* __restrict__ nf,
                     unsigned short* __restrict__ ws, int do_nf) {
    unsigned short* w1t = ws;
    unsigned short* w2t = ws + 10240;
    unsigned short* w3t = ws + 12288;
    int t = blockIdx.x * blockDim.x + threadIdx.x;
    int stride = gridDim.x * blockDim.x;
    for (int i = t; i < 64 * 160; i += stride) {
        int j = i / 160, k = i % 160;
        w1t[i] = f2bf_bits(k < 130 ? W1[k * 64 + j] : 0.0f);
    }
    for (int i = t; i < 32 * 64; i += stride) {
        int j = i / 64, k = i % 64;
        w2t[i] = f2bf_bits(W2[k * 32 + j]);
    }
    for (int i = t; i < 16 * 32; i += stride) {
        int j = i / 32, k = i % 32;
        w3t[i] = f2bf_bits(W3[k * 16 + j]);
    }
    if (do_nf) {
        unsigned short* nfb = ws + TAB_OFF;
        for (int i = t; i < NN * 8; i += stride) {
            f32x4 a = *reinterpret_cast<const f32x4*>(nf + (long)i * 8);
            f32x4 b = *reinterpret_cast<const f32x4*>(nf + (long)i * 8 + 4);
            *reinterpret_cast<s16x8*>(nfb + (long)i * 8) = cvt8(a, b);
        }
    }
}

template <bool BF16NF>
__device__ __forceinline__ void gather4(const unsigned short* nfb, const float* nf,
                                        int si, int di, int lg, s16x8 g[4]) {
    if (BF16NF) {
        #pragma unroll
        for (int s = 0; s < 4; ++s) {
            const int row = (s < 2) ? si : di;
            g[s] = *reinterpret_cast<const s16x8*>(nfb + (long)row * 64 + (s & 1) * 32 + lg * 8);
        }
    } else {
        #pragma unroll
        for (int s = 0; s < 4; ++s) {
            const float* p = nf + (long)((s < 2) ? si : di) * 64 + (s & 1) * 32 + lg * 8;
            f32x4 a = *reinterpret_cast<const f32x4*>(p);
            f32x4 b = *reinterpret_cast<const f32x4*>(p + 4);
            g[s] = cvt8(a, b);
        }
    }
}

template <bool BF16NF>
__global__ __launch_bounds__(256) void edge_mlp_fb(
    const float* __restrict__ nf, const int* __restrict__ ei,
    const float* __restrict__ sp, const float* __restrict__ b1,
    const float* __restrict__ b2, const float* __restrict__ b3,
    const unsigned short* __restrict__ wsw, float* __restrict__ out) {

    const unsigned short* w1t = wsw;
    const unsigned short* w2t = wsw + 10240;
    const unsigned short* w3t = wsw + 12288;
    const unsigned short* nfb = wsw + TAB_OFF;

    __shared__ float h1s[4][16][68];
    __shared__ float h2s[4][16][36];

    const int tid = threadIdx.x, wid = tid >> 6, lane = tid & 63;
    const int lr = lane & 15, lg = lane >> 4;

    s16x8 w1f[5][4], w2f[2][2], w3f;
    #pragma unroll
    for (int s = 0; s < 5; ++s)
        #pragma unroll
        for (int c = 0; c < 4; ++c)
            w1f[s][c] = *reinterpret_cast<const s16x8*>(w1t + (c * 16 + lr) * 160 + s * 32 + lg * 8);
    #pragma unroll
    for (int s = 0; s < 2; ++s)
        #pragma unroll
        for (int c = 0; c < 2; ++c)
            w2f[s][c] = *reinterpret_cast<const s16x8*>(w2t + (c * 16 + lr) * 64 + s * 32 + lg * 8);
    w3f = *reinterpret_cast<const s16x8*>(w3t + lr * 32 + lg * 8);

    float bias1[4], bias2[2], bias3;
    #pragma unroll
    for (int c = 0; c < 4; ++c) bias1[c] = b1[c * 16 + lr];
    #pragma unroll
    for (int c = 0; c < 2; ++c) bias2[c] = b2[c * 16 + lr];
    bias3 = b3[lr];

    const int tile0 = (blockIdx.x * 4 + wid) * 4;
    int si[4], di[4];
    f32x2 spv[4];
    #pragma unroll
    for (int t = 0; t < 4; ++t) {
        const int e = (tile0 + t) * 16 + lr;
        si[t] = ei[e];
        di[t] = ei[NE + e];
        spv[t] = *reinterpret_cast<const f32x2*>(sp + 2 * (size_t)e);
    }

    s16x8 cur[4], nxt[4];
    gather4<BF16NF>(nfb, nf, si[0], di[0], lg, cur);

    #pragma unroll
    for (int tt = 0; tt < 4; ++tt) {
        if (tt + 1 < 4)
            gather4<BF16NF>(nfb, nf, si[tt + 1], di[tt + 1], lg, nxt);

        const int ebase = (tile0 + tt) * 16;

        f32x4 acc1[4];
        #pragma unroll
        for (int c = 0; c < 4; ++c) acc1[c] = (f32x4){0, 0, 0, 0};
        #pragma unroll
        for (int s = 0; s < 4; ++s)
            #pragma unroll
            for (int c = 0; c < 4; ++c)
                acc1[c] = __builtin_amdgcn_mfma_f32_16x16x32_bf16(cur[s], w1f[s][c], acc1[c], 0, 0, 0);
        {
            bf16x8 z;
            #pragma unroll
            for (int j = 0; j < 8; ++j) z[j] = (__bf16)0.0f;
            if (lg == 0) { z[0] = (__bf16)spv[tt][0]; z[1] = (__bf16)spv[tt][1]; }
            s16x8 af = __builtin_bit_cast(s16x8, z);
            #pragma unroll
            for (int c = 0; c < 4; ++c)
                acc1[c] = __builtin_amdgcn_mfma_f32_16x16x32_bf16(af, w1f[4][c], acc1[c], 0, 0, 0);
        }
        #pragma unroll
        for (int c = 0; c < 4; ++c)
            #pragma unroll
            for (int r = 0; r < 4; ++r)
                h1s[wid][lg * 4 + r][c * 16 + lr] = fmaxf(acc1[c][r] + bias1[c], 0.0f);

        f32x4 acc2[2];
        #pragma unroll
        for (int c = 0; c < 2; ++c) acc2[c] = (f32x4){0, 0, 0, 0};
        #pragma unroll
        for (int s = 0; s < 2; ++s) {
            f32x4 a = *reinterpret_cast<const f32x4*>(&h1s[wid][lr][s * 32 + lg * 8]);
            f32x4 b = *reinterpret_cast<const f32x4*>(&h1s[wid][lr][s * 32 + lg * 8 + 4]);
            s16x8 af = cvt8(a, b);
            #pragma unroll
            for (int c = 0; c < 2; ++c)
                acc2[c] = __builtin_amdgcn_mfma_f32_16x16x32_bf16(af, w2f[s][c], acc2[c], 0, 0, 0);
        }
        #pragma unroll
        for (int c = 0; c < 2; ++c)
            #pragma unroll
            for (int r = 0; r < 4; ++r)
                h2s[wid][lg * 4 + r][c * 16 + lr] = fmaxf(acc2[c][r] + bias2[c], 0.0f);

        f32x4 a3 = *reinterpret_cast<const f32x4*>(&h2s[wid][lr][lg * 8]);
        f32x4 b3x = *reinterpret_cast<const f32x4*>(&h2s[wid][lr][lg * 8 + 4]);
        s16x8 af3 = cvt8(a3, b3x);
        f32x4 acc3 = (f32x4){0, 0, 0, 0};
        acc3 = __builtin_amdgcn_mfma_f32_16x16x32_bf16(af3, w3f, acc3, 0, 0, 0);
        #pragma unroll
        for (int r = 0; r < 4; ++r)
            out[(long)(ebase + lg * 4 + r) * 16 + lr] = acc3[r] + bias3;

        #pragma unroll
        for (int s = 0; s < 4; ++s) cur[s] = nxt[s];
    }
}

extern "C" void kernel_launch(void* const* d_in, const int* in_sizes, int n_in,
                              void* d_out, int out_size, void* d_ws, size_t ws_size,
                              hipStream_t stream) {
    const float* nf = (const float*)d_in[0];
    const int*   ei = (const int*)d_in[1];
    const float* sp = (const float*)d_in[2];
    const float* W1 = (const float*)d_in[3];
    const float* b1 = (const float*)d_in[4];
    const float* W2 = (const float*)d_in[5];
    const float* b2 = (const float*)d_in[6];
    const float* W3 = (const float*)d_in[7];
    const float* b3 = (const float*)d_in[8];
    float* out = (float*)d_out;
    unsigned short* wsw = (unsigned short*)d_ws;

    const bool tab  = (ws_size >= WS_TAB);
    const bool bnfb = (!tab && ws_size >= WS_NFB);

    if (tab) {
        // try the single fused cooperative kernel
        bool done = false;
        int maxb = 0, ncu = 0;
        if (hipOccupancyMaxActiveBlocksPerMultiprocessor(
                &maxb, (const void*)fused_all, 256, 0) == hipSuccess &&
            hipDeviceGetAttribute(&ncu, hipDeviceAttributeMultiprocessorCount, 0)
                == hipSuccess && maxb > 0 && ncu > 0) {
            int grid = maxb * ncu;
            if (grid > 2048) grid = 2048;
            unsigned short* tabp = wsw + TAB_OFF;
            void* args[] = {(void*)&nf, (void*)&ei, (void*)&sp, (void*)&W1,
                            (void*)&b1, (void*)&W2, (void*)&b2, (void*)&W3,
                            (void*)&b3, (void*)&tabp, (void*)&out};
            hipError_t le = hipLaunchCooperativeKernel(
                (const void*)fused_all, dim3(grid), dim3(256), args, 0, stream);
            done = (le == hipSuccess);
        }
        if (!done) {   // proven R6 two-kernel path
            const int pblocks = (NODE_TILES + 3) / 4;
            hipLaunchKernelGGL(node_prep_all, dim3(pblocks), dim3(256), 0, stream,
                               nf, W1, b1, W2, W3, wsw);
            const int blocks = NTILES / TPW / 4;
            hipLaunchKernelGGL(edge_mlp_tab, dim3(blocks), dim3(256), 0, stream,
                               ei, sp, W1, b2, b3, wsw, out);
        }
    } else {
        hipLaunchKernelGGL(prep, dim3(64), dim3(256), 0, stream,
                           W1, W2, W3, nf, wsw, bnfb ? 1 : 0);
        const int blocks = NTILES / 4 / 4;
        if (bnfb)
            hipLaunchKernelGGL(edge_mlp_fb<true>, dim3(blocks), dim3(256), 0, stream,
                               nf, ei, sp, b1, b2, b3, wsw, out);
        else
            hipLaunchKernelGGL(edge_mlp_fb<false>, dim3(blocks), dim3(256), 0, stream,
                               nf, ei, sp, b1, b2, b3, wsw, out);
    }
}

// Round 9
// 59.071 us; speedup vs baseline: 3.0295x; 3.0295x over previous
//
#include <hip/hip_runtime.h>
#include <hip/hip_bf16.h>

#define NE 800000   // edges
#define NN 50000    // nodes
#define TPW 4       // edge-tiles (of 16 edges) per wave
#define NTILES (NE / 16)       // 50000
#define NODE_TILES (NN / 16)   // 3125

typedef __attribute__((ext_vector_type(8))) short        s16x8;
typedef __attribute__((ext_vector_type(4))) short        s16x4;
typedef __attribute__((ext_vector_type(8))) __bf16       bf16x8;
typedef __attribute__((ext_vector_type(4))) __bf16       bf16x4;
typedef __attribute__((ext_vector_type(4))) float        f32x4;
typedef __attribute__((ext_vector_type(2))) float        f32x2;
typedef __attribute__((ext_vector_type(4))) unsigned int u32x4;
typedef __attribute__((ext_vector_type(2))) unsigned int u32x2;

// ws layout (unsigned short elems):
//   [0)      w1t region (fallback weight packs)
//   [10240)  w2t [32][64]
//   [12288)  w3t [16][32]
//   [16384)  At [NN][64] bf16 (nf @ W1[0:64] + b1); then Bt [NN][64]
#define TAB_OFF 16384
#define WS_TAB ((size_t)(TAB_OFF + 2ull * NN * 64) * 2)
#define WS_NFB ((size_t)(TAB_OFF + 1ull * NN * 64) * 2)

__device__ __forceinline__ unsigned short f2bf_bits(float f) {
    __bf16 b = (__bf16)f;
    return __builtin_bit_cast(unsigned short, b);
}

__device__ __forceinline__ unsigned int pkbf(float a, float b) {
    return (unsigned int)f2bf_bits(a) | ((unsigned int)f2bf_bits(b) << 16);
}

__device__ __forceinline__ s16x8 cvt8(f32x4 a, f32x4 b) {
    bf16x8 r;
    r[0] = (__bf16)a[0]; r[1] = (__bf16)a[1]; r[2] = (__bf16)a[2]; r[3] = (__bf16)a[3];
    r[4] = (__bf16)b[0]; r[5] = (__bf16)b[1]; r[6] = (__bf16)b[2]; r[7] = (__bf16)b[3];
    return __builtin_bit_cast(s16x8, r);
}

// ---- prep: tables + weight packs, one kernel (R6 shape, cheap staging) ----
__global__ __launch_bounds__(256) void node_prep_all(
    const float* __restrict__ nf, const float* __restrict__ W1,
    const float* __restrict__ b1, const float* __restrict__ W2,
    const float* __restrict__ W3, unsigned short* __restrict__ ws) {
    unsigned short* w2t = ws + 10240;
    unsigned short* w3t = ws + 12288;
    unsigned short* At  = ws + TAB_OFF;
    unsigned short* Bt  = At + (size_t)NN * 64;

    __shared__ unsigned short w1l[128 * 64];   // [k][j] bf16, 16 KiB

    const int tid = threadIdx.x, wid = tid >> 6, lane = tid & 63;
    const int lr = lane & 15, lg = lane >> 4;

    // stage W1[0:128][0:64] -> LDS [k][j]: f32x4 loads + b64 packed writes, 8 iters
    #pragma unroll
    for (int it = 0; it < 8; ++it) {
        const int i = it * 1024 + tid * 4;   // 4 consecutive j, same k
        f32x4 v = *reinterpret_cast<const f32x4*>(W1 + i);
        bf16x4 p;
        p[0] = (__bf16)v[0]; p[1] = (__bf16)v[1];
        p[2] = (__bf16)v[2]; p[3] = (__bf16)v[3];
        *reinterpret_cast<s16x4*>(&w1l[i]) = __builtin_bit_cast(s16x4, p);
    }
    __syncthreads();

    if (blockIdx.x == 0) {   // pack small weights once
        for (int i = tid; i < 32 * 64; i += 256) {
            int j = i / 64, k = i % 64;
            w2t[i] = f2bf_bits(W2[k * 32 + j]);
        }
        for (int i = tid; i < 16 * 32; i += 256) {
            int j = i / 32, k = i % 32;
            w3t[i] = f2bf_bits(W3[k * 16 + j]);
        }
    }

    // A-frags: lane holds W1^T[j=c*16+lr][k=s*32+lg*8+b] -> 8 ds_read_u16 each
    s16x8 w1f[4][4];
    #pragma unroll
    for (int s = 0; s < 4; ++s)
        #pragma unroll
        for (int c = 0; c < 4; ++c) {
            bf16x8 w;
            #pragma unroll
            for (int b = 0; b < 8; ++b)
                w[b] = __builtin_bit_cast(__bf16, w1l[(s * 32 + lg * 8 + b) * 64 + c * 16 + lr]);
            w1f[s][c] = __builtin_bit_cast(s16x8, w);
        }

    f32x4 b1q[4];
    #pragma unroll
    for (int c = 0; c < 4; ++c)
        b1q[c] = *reinterpret_cast<const f32x4*>(b1 + c * 16 + lg * 4);

    const int tile = blockIdx.x * 4 + wid;   // 1 node-tile per wave
    if (tile >= NODE_TILES) return;

    const int row = tile * 16 + lr;
    const float* p = nf + (long)row * 64;
    s16x8 nfr[2];
    #pragma unroll
    for (int s = 0; s < 2; ++s) {
        f32x4 a = *reinterpret_cast<const f32x4*>(p + s * 32 + lg * 8);
        f32x4 b = *reinterpret_cast<const f32x4*>(p + s * 32 + lg * 8 + 4);
        nfr[s] = cvt8(a, b);
    }
    f32x4 a4[4], b4[4];
    #pragma unroll
    for (int c = 0; c < 4; ++c) { a4[c] = (f32x4){0,0,0,0}; b4[c] = (f32x4){0,0,0,0}; }
    #pragma unroll
    for (int s = 0; s < 2; ++s)
        #pragma unroll
        for (int c = 0; c < 4; ++c) {
            a4[c] = __builtin_amdgcn_mfma_f32_16x16x32_bf16(w1f[s][c],     nfr[s], a4[c], 0, 0, 0);
            b4[c] = __builtin_amdgcn_mfma_f32_16x16x32_bf16(w1f[s + 2][c], nfr[s], b4[c], 0, 0, 0);
        }
    // D: lane holds feat j=c*16+lg*4+r of node=row; b1 folded into At
    #pragma unroll
    for (int c = 0; c < 4; ++c) {
        u32x2 pa, pb;
        pa[0] = pkbf(a4[c][0] + b1q[c][0], a4[c][1] + b1q[c][1]);
        pa[1] = pkbf(a4[c][2] + b1q[c][2], a4[c][3] + b1q[c][3]);
        pb[0] = pkbf(b4[c][0], b4[c][1]);
        pb[1] = pkbf(b4[c][2], b4[c][3]);
        *reinterpret_cast<u32x2*>(At + (long)row * 64 + c * 16 + lg * 4) = pa;
        *reinterpret_cast<u32x2*>(Bt + (long)row * 64 + c * 16 + lg * 4) = pb;
    }
}

__device__ __forceinline__ void gatherT(const unsigned short* At, const unsigned short* Bt,
                                        int si, int di, int lg, s16x8 g[4]) {
    const unsigned short* pa = At + (size_t)si * 64 + lg * 8;
    const unsigned short* pb = Bt + (size_t)di * 64 + lg * 8;
    g[0] = *reinterpret_cast<const s16x8*>(pa);
    g[1] = *reinterpret_cast<const s16x8*>(pa + 32);
    g[2] = *reinterpret_cast<const s16x8*>(pb);
    g[3] = *reinterpret_cast<const s16x8*>(pb + 32);
}

__device__ __forceinline__ void compute_tile(
    int tile, const s16x8 cur[4], f32x2 s2,
    const f32x2 c0p[2][4], const f32x2 c1p[2][4],
    const s16x8 w2f[2][2], s16x8 w3f,
    const f32x4 b2v[2], f32x4 b3v,
    unsigned short* h2w, int lg, int lr, float* __restrict__ out) {

    const f32x2 sp0v = {s2[0], s2[0]}, sp1v = {s2[1], s2[1]};

    s16x8 bfr[2];
    #pragma unroll
    for (int jb = 0; jb < 2; ++jb) {
        u32x4 au = __builtin_bit_cast(u32x4, cur[jb]);
        u32x4 bu = __builtin_bit_cast(u32x4, cur[2 + jb]);
        u32x4 pk4;
        #pragma unroll
        for (int q = 0; q < 4; ++q) {
            f32x2 av = {__builtin_bit_cast(float, au[q] << 16),
                        __builtin_bit_cast(float, au[q] & 0xFFFF0000u)};
            f32x2 bv = {__builtin_bit_cast(float, bu[q] << 16),
                        __builtin_bit_cast(float, bu[q] & 0xFFFF0000u)};
            f32x2 h = av + bv;
            h = sp1v * c1p[jb][q] + h;
            h = sp0v * c0p[jb][q] + h;
            pk4[q] = pkbf(fmaxf(h[0], 0.f), fmaxf(h[1], 0.f));
        }
        bfr[jb] = __builtin_bit_cast(s16x8, pk4);
    }

    f32x4 acc2[2];
    #pragma unroll
    for (int c = 0; c < 2; ++c) acc2[c] = (f32x4){0, 0, 0, 0};
    #pragma unroll
    for (int s = 0; s < 2; ++s)
        #pragma unroll
        for (int c = 0; c < 2; ++c)
            acc2[c] = __builtin_amdgcn_mfma_f32_16x16x32_bf16(w2f[s][c], bfr[s], acc2[c], 0, 0, 0);

    #pragma unroll
    for (int c = 0; c < 2; ++c) {
        u32x2 p;
        p[0] = pkbf(fmaxf(acc2[c][0] + b2v[c][0], 0.f), fmaxf(acc2[c][1] + b2v[c][1], 0.f));
        p[1] = pkbf(fmaxf(acc2[c][2] + b2v[c][2], 0.f), fmaxf(acc2[c][3] + b2v[c][3], 0.f));
        *reinterpret_cast<u32x2*>(h2w + c * 16 + lg * 4) = p;
    }

    s16x8 bf3 = *reinterpret_cast<const s16x8*>(h2w + lg * 8);
    f32x4 acc3 = (f32x4){0, 0, 0, 0};
    acc3 = __builtin_amdgcn_mfma_f32_16x16x32_bf16(w3f, bf3, acc3, 0, 0, 0);

    f32x4 o;
    #pragma unroll
    for (int r = 0; r < 4; ++r) o[r] = acc3[r] + b3v[r];
    __builtin_nontemporal_store(o,
        reinterpret_cast<f32x4*>(out + (long)(tile * 16 + lr) * 16 + lg * 4));
}

// ---- edge kernel: TPW=4, full idx prologue, DEPTH-2 gather pipeline ----
__global__ __launch_bounds__(256) void edge_mlp_tab(
    const int* __restrict__ ei, const float* __restrict__ sp,
    const float* __restrict__ W1, const float* __restrict__ b2,
    const float* __restrict__ b3, const unsigned short* __restrict__ wsw,
    float* __restrict__ out) {

    const unsigned short* w2t = wsw + 10240;
    const unsigned short* w3t = wsw + 12288;
    const unsigned short* At  = wsw + TAB_OFF;
    const unsigned short* Bt  = At + (size_t)NN * 64;

    __shared__ unsigned short h2s[4 * 16 * 40];   // 5120 B, per-wave regions

    const int tid = threadIdx.x, wid = tid >> 6, lane = tid & 63;
    const int lr = lane & 15, lg = lane >> 4;

    const int tile0 = (blockIdx.x * 4 + wid) * TPW;

    s16x8 w2f[2][2], w3f;
    #pragma unroll
    for (int s = 0; s < 2; ++s)
        #pragma unroll
        for (int c = 0; c < 2; ++c)
            w2f[s][c] = *reinterpret_cast<const s16x8*>(w2t + (c * 16 + lr) * 64 + s * 32 + lg * 8);
    w3f = *reinterpret_cast<const s16x8*>(w3t + lr * 32 + lg * 8);

    f32x4 b2v[2];
    #pragma unroll
    for (int c = 0; c < 2; ++c) b2v[c] = *reinterpret_cast<const f32x4*>(b2 + c * 16 + lg * 4);
    const f32x4 b3v = *reinterpret_cast<const f32x4*>(b3 + lg * 4);

    // spatial-row consts as f32x2 pairs (feats j = jb*32 + lg*8 + 2q, 2q+1)
    f32x2 c0p[2][4], c1p[2][4];
    #pragma unroll
    for (int jb = 0; jb < 2; ++jb) {
        const int j0 = jb * 32 + lg * 8;
        f32x4 x0 = *reinterpret_cast<const f32x4*>(W1 + 128 * 64 + j0);
        f32x4 x1 = *reinterpret_cast<const f32x4*>(W1 + 128 * 64 + j0 + 4);
        f32x4 y0 = *reinterpret_cast<const f32x4*>(W1 + 129 * 64 + j0);
        f32x4 y1 = *reinterpret_cast<const f32x4*>(W1 + 129 * 64 + j0 + 4);
        c0p[jb][0] = (f32x2){x0[0], x0[1]}; c0p[jb][1] = (f32x2){x0[2], x0[3]};
        c0p[jb][2] = (f32x2){x1[0], x1[1]}; c0p[jb][3] = (f32x2){x1[2], x1[3]};
        c1p[jb][0] = (f32x2){y0[0], y0[1]}; c1p[jb][1] = (f32x2){y0[2], y0[3]};
        c1p[jb][2] = (f32x2){y1[0], y1[1]}; c1p[jb][3] = (f32x2){y1[2], y1[3]};
    }

    unsigned short* h2w = h2s + wid * (16 * 40) + lr * 40;

    // prologue: all TPW tiles' indices + spatial at once (batch latency)
    int si[TPW], di[TPW];
    f32x2 spv[TPW];
    #pragma unroll
    for (int t = 0; t < TPW; ++t) {
        const size_t e = (size_t)(tile0 + t) * 16 + lr;
        si[t] = ei[e];
        di[t] = ei[NE + e];
        spv[t] = *reinterpret_cast<const f32x2*>(sp + 2 * e);
    }

    // depth-2 pipeline: two gathers in flight ahead of each compute
    s16x8 g0[4], g1[4], g2[4];
    gatherT(At, Bt, si[0], di[0], lg, g0);
    gatherT(At, Bt, si[1], di[1], lg, g1);

    gatherT(At, Bt, si[2], di[2], lg, g2);
    compute_tile(tile0 + 0, g0, spv[0], c0p, c1p, w2f, w3f, b2v, b3v, h2w, lg, lr, out);

    gatherT(At, Bt, si[3], di[3], lg, g0);
    compute_tile(tile0 + 1, g1, spv[1], c0p, c1p, w2f, w3f, b2v, b3v, h2w, lg, lr, out);

    compute_tile(tile0 + 2, g2, spv[2], c0p, c1p, w2f, w3f, b2v, b3v, h2w, lg, lr, out);
    compute_tile(tile0 + 3, g0, spv[3], c0p, c1p, w2f, w3f, b2v, b3v, h2w, lg, lr, out);
}

// ---------------- small-ws fallback (R2 kernel, proven) ----------------
__global__ void prep(const float* __restrict__ W1, const float* __restrict__ W2,
                     const float* __restrict__ W3, const float* __restrict__ nf,
                     unsigned short* __restrict__ ws, int do_nf) {
    unsigned short* w1t = ws;
    unsigned short* w2t = ws + 10240;
    unsigned short* w3t = ws + 12288;
    int t = blockIdx.x * blockDim.x + threadIdx.x;
    int stride = gridDim.x * blockDim.x;
    for (int i = t; i < 64 * 160; i += stride) {
        int j = i / 160, k = i % 160;
        w1t[i] = f2bf_bits(k < 130 ? W1[k * 64 + j] : 0.0f);
    }
    for (int i = t; i < 32 * 64; i += stride) {
        int j = i / 64, k = i % 64;
        w2t[i] = f2bf_bits(W2[k * 32 + j]);
    }
    for (int i = t; i < 16 * 32; i += stride) {
        int j = i / 32, k = i % 32;
        w3t[i] = f2bf_bits(W3[k * 16 + j]);
    }
    if (do_nf) {
        unsigned short* nfb = ws + TAB_OFF;
        for (int i = t; i < NN * 8; i += stride) {
            f32x4 a = *reinterpret_cast<const f32x4*>(nf + (long)i * 8);
            f32x4 b = *reinterpret_cast<const f32x4*>(nf + (long)i * 8 + 4);
            *reinterpret_cast<s16x8*>(nfb + (long)i * 8) = cvt8(a, b);
        }
    }
}

template <bool BF16NF>
__device__ __forceinline__ void gather4(const unsigned short* nfb, const float* nf,
                                        int si, int di, int lg, s16x8 g[4]) {
    if (BF16NF) {
        #pragma unroll
        for (int s = 0; s < 4; ++s) {
            const int row = (s < 2) ? si : di;
            g[s] = *reinterpret_cast<const s16x8*>(nfb + (long)row * 64 + (s & 1) * 32 + lg * 8);
        }
    } else {
        #pragma unroll
        for (int s = 0; s < 4; ++s) {
            const float* p = nf + (long)((s < 2) ? si : di) * 64 + (s & 1) * 32 + lg * 8;
            f32x4 a = *reinterpret_cast<const f32x4*>(p);
            f32x4 b = *reinterpret_cast<const f32x4*>(p + 4);
            g[s] = cvt8(a, b);
        }
    }
}

template <bool BF16NF>
__global__ __launch_bounds__(256) void edge_mlp_fb(
    const float* __restrict__ nf, const int* __restrict__ ei,
    const float* __restrict__ sp, const float* __restrict__ b1,
    const float* __restrict__ b2, const float* __restrict__ b3,
    const unsigned short* __restrict__ wsw, float* __restrict__ out) {

    const unsigned short* w1t = wsw;
    const unsigned short* w2t = wsw + 10240;
    const unsigned short* w3t = wsw + 12288;
    const unsigned short* nfb = wsw + TAB_OFF;

    __shared__ float h1s[4][16][68];
    __shared__ float h2s[4][16][36];

    const int tid = threadIdx.x, wid = tid >> 6, lane = tid & 63;
    const int lr = lane & 15, lg = lane >> 4;

    s16x8 w1f[5][4], w2f[2][2], w3f;
    #pragma unroll
    for (int s = 0; s < 5; ++s)
        #pragma unroll
        for (int c = 0; c < 4; ++c)
            w1f[s][c] = *reinterpret_cast<const s16x8*>(w1t + (c * 16 + lr) * 160 + s * 32 + lg * 8);
    #pragma unroll
    for (int s = 0; s < 2; ++s)
        #pragma unroll
        for (int c = 0; c < 2; ++c)
            w2f[s][c] = *reinterpret_cast<const s16x8*>(w2t + (c * 16 + lr) * 64 + s * 32 + lg * 8);
    w3f = *reinterpret_cast<const s16x8*>(w3t + lr * 32 + lg * 8);

    float bias1[4], bias2[2], bias3;
    #pragma unroll
    for (int c = 0; c < 4; ++c) bias1[c] = b1[c * 16 + lr];
    #pragma unroll
    for (int c = 0; c < 2; ++c) bias2[c] = b2[c * 16 + lr];
    bias3 = b3[lr];

    const int tile0 = (blockIdx.x * 4 + wid) * 4;
    int si[4], di[4];
    f32x2 spv[4];
    #pragma unroll
    for (int t = 0; t < 4; ++t) {
        const int e = (tile0 + t) * 16 + lr;
        si[t] = ei[e];
        di[t] = ei[NE + e];
        spv[t] = *reinterpret_cast<const f32x2*>(sp + 2 * (size_t)e);
    }

    s16x8 cur[4], nxt[4];
    gather4<BF16NF>(nfb, nf, si[0], di[0], lg, cur);

    #pragma unroll
    for (int tt = 0; tt < 4; ++tt) {
        if (tt + 1 < 4)
            gather4<BF16NF>(nfb, nf, si[tt + 1], di[tt + 1], lg, nxt);

        const int ebase = (tile0 + tt) * 16;

        f32x4 acc1[4];
        #pragma unroll
        for (int c = 0; c < 4; ++c) acc1[c] = (f32x4){0, 0, 0, 0};
        #pragma unroll
        for (int s = 0; s < 4; ++s)
            #pragma unroll
            for (int c = 0; c < 4; ++c)
                acc1[c] = __builtin_amdgcn_mfma_f32_16x16x32_bf16(cur[s], w1f[s][c], acc1[c], 0, 0, 0);
        {
            bf16x8 z;
            #pragma unroll
            for (int j = 0; j < 8; ++j) z[j] = (__bf16)0.0f;
            if (lg == 0) { z[0] = (__bf16)spv[tt][0]; z[1] = (__bf16)spv[tt][1]; }
            s16x8 af = __builtin_bit_cast(s16x8, z);
            #pragma unroll
            for (int c = 0; c < 4; ++c)
                acc1[c] = __builtin_amdgcn_mfma_f32_16x16x32_bf16(af, w1f[4][c], acc1[c], 0, 0, 0);
        }
        #pragma unroll
        for (int c = 0; c < 4; ++c)
            #pragma unroll
            for (int r = 0; r < 4; ++r)
                h1s[wid][lg * 4 + r][c * 16 + lr] = fmaxf(acc1[c][r] + bias1[c], 0.0f);

        f32x4 acc2[2];
        #pragma unroll
        for (int c = 0; c < 2; ++c) acc2[c] = (f32x4){0, 0, 0, 0};
        #pragma unroll
        for (int s = 0; s < 2; ++s) {
            f32x4 a = *reinterpret_cast<const f32x4*>(&h1s[wid][lr][s * 32 + lg * 8]);
            f32x4 b = *reinterpret_cast<const f32x4*>(&h1s[wid][lr][s * 32 + lg * 8 + 4]);
            s16x8 af = cvt8(a, b);
            #pragma unroll
            for (int c = 0; c < 2; ++c)
                acc2[c] = __builtin_amdgcn_mfma_f32_16x16x32_bf16(af, w2f[s][c], acc2[c], 0, 0, 0);
        }
        #pragma unroll
        for (int c = 0; c < 2; ++c)
            #pragma unroll
            for (int r = 0; r < 4; ++r)
                h2s[wid][lg * 4 + r][c * 16 + lr] = fmaxf(acc2[c][r] + bias2[c], 0.0f);

        f32x4 a3 = *reinterpret_cast<const f32x4*>(&h2s[wid][lr][lg * 8]);
        f32x4 b3x = *reinterpret_cast<const f32x4*>(&h2s[wid][lr][lg * 8 + 4]);
        s16x8 af3 = cvt8(a3, b3x);
        f32x4 acc3 = (f32x4){0, 0, 0, 0};
        acc3 = __builtin_amdgcn_mfma_f32_16x16x32_bf16(af3, w3f, acc3, 0, 0, 0);
        #pragma unroll
        for (int r = 0; r < 4; ++r)
            out[(long)(ebase + lg * 4 + r) * 16 + lr] = acc3[r] + bias3;

        #pragma unroll
        for (int s = 0; s < 4; ++s) cur[s] = nxt[s];
    }
}

extern "C" void kernel_launch(void* const* d_in, const int* in_sizes, int n_in,
                              void* d_out, int out_size, void* d_ws, size_t ws_size,
                              hipStream_t stream) {
    const float* nf = (const float*)d_in[0];
    const int*   ei = (const int*)d_in[1];
    const float* sp = (const float*)d_in[2];
    const float* W1 = (const float*)d_in[3];
    const float* b1 = (const float*)d_in[4];
    const float* W2 = (const float*)d_in[5];
    const float* b2 = (const float*)d_in[6];
    const float* W3 = (const float*)d_in[7];
    const float* b3 = (const float*)d_in[8];
    float* out = (float*)d_out;
    unsigned short* wsw = (unsigned short*)d_ws;

    const bool tab  = (ws_size >= WS_TAB);
    const bool bnfb = (!tab && ws_size >= WS_NFB);

    if (tab) {
        const int pblocks = (NODE_TILES + 3) / 4;   // 782, 1 tile/wave
        hipLaunchKernelGGL(node_prep_all, dim3(pblocks), dim3(256), 0, stream,
                           nf, W1, b1, W2, W3, wsw);
        const int blocks = NTILES / TPW / 4;        // 3125
        hipLaunchKernelGGL(edge_mlp_tab, dim3(blocks), dim3(256), 0, stream,
                           ei, sp, W1, b2, b3, wsw, out);
    } else {
        hipLaunchKernelGGL(prep, dim3(64), dim3(256), 0, stream,
                           W1, W2, W3, nf, wsw, bnfb ? 1 : 0);
        const int blocks = NTILES / 4 / 4;   // 3125
        if (bnfb)
            hipLaunchKernelGGL(edge_mlp_fb<true>, dim3(blocks), dim3(256), 0, stream,
                               nf, ei, sp, b1, b2, b3, wsw, out);
        else
            hipLaunchKernelGGL(edge_mlp_fb<false>, dim3(blocks), dim3(256), 0, stream,
                               nf, ei, sp, b1, b2, b3, wsw, out);
    }
}

// Round 10
// 57.075 us; speedup vs baseline: 3.1354x; 1.0350x over previous
//
#include <hip/hip_runtime.h>
#include <hip/hip_bf16.h>

#define NE 800000   // edges
#define NN 50000    // nodes
#define TPW 5       // edge-tiles (of 16 edges) per wave (50000/20 = 2500 blocks)
#define NTILES (NE / 16)       // 50000
#define NODE_TILES (NN / 16)   // 3125
#define W1STR 136              // LDS row stride (shorts), b128-aligned

typedef __attribute__((ext_vector_type(8))) short        s16x8;
typedef __attribute__((ext_vector_type(4))) short        s16x4;
typedef __attribute__((ext_vector_type(8))) __bf16       bf16x8;
typedef __attribute__((ext_vector_type(4))) __bf16       bf16x4;
typedef __attribute__((ext_vector_type(4))) float        f32x4;
typedef __attribute__((ext_vector_type(2))) float        f32x2;
typedef __attribute__((ext_vector_type(4))) unsigned int u32x4;
typedef __attribute__((ext_vector_type(2))) unsigned int u32x2;

// ws layout (unsigned short elems):
//   [0)      w1t region (fallback weight packs)
//   [10240)  w2t [32][64]
//   [12288)  w3t [16][32]
//   [16384)  At [NN][64] bf16 (nf @ W1[0:64] + b1); then Bt [NN][64]
#define TAB_OFF 16384
#define WS_TAB ((size_t)(TAB_OFF + 2ull * NN * 64) * 2)
#define WS_NFB ((size_t)(TAB_OFF + 1ull * NN * 64) * 2)

__device__ __forceinline__ unsigned short f2bf_bits(float f) {
    __bf16 b = (__bf16)f;
    return __builtin_bit_cast(unsigned short, b);
}

__device__ __forceinline__ unsigned int pkbf(float a, float b) {
    return (unsigned int)f2bf_bits(a) | ((unsigned int)f2bf_bits(b) << 16);
}

__device__ __forceinline__ s16x8 cvt8(f32x4 a, f32x4 b) {
    bf16x8 r;
    r[0] = (__bf16)a[0]; r[1] = (__bf16)a[1]; r[2] = (__bf16)a[2]; r[3] = (__bf16)a[3];
    r[4] = (__bf16)b[0]; r[5] = (__bf16)b[1]; r[6] = (__bf16)b[2]; r[7] = (__bf16)b[3];
    return __builtin_bit_cast(s16x8, r);
}

// swizzled LDS address for W1^T element (k, j):
//   addr = j*W1STR + ((k>>3) ^ ((j>>2)&15))*8 + (k&7)
__device__ __forceinline__ int w1addr(int k, int j) {
    return j * W1STR + (((k >> 3) ^ ((j >> 2) & 15)) << 3) + (k & 7);
}

// ---- prep: tables + weight packs, one kernel. Transposed+swizzled W1 staging ----
__global__ __launch_bounds__(256) void node_prep_all(
    const float* __restrict__ nf, const float* __restrict__ W1,
    const float* __restrict__ b1, const float* __restrict__ W2,
    const float* __restrict__ W3, unsigned short* __restrict__ ws) {
    unsigned short* w2t = ws + 10240;
    unsigned short* w3t = ws + 12288;
    unsigned short* At  = ws + TAB_OFF;
    unsigned short* Bt  = At + (size_t)NN * 64;

    __shared__ unsigned short w1l[64 * W1STR];   // [j][k] bf16 swizzled, 17.4 KiB

    const int tid = threadIdx.x, wid = tid >> 6, lane = tid & 63;
    const int lr = lane & 15, lg = lane >> 4;

    // stage W1[0:128][0:64] -> LDS transposed: f32x4 coalesced loads,
    // 4 swizzled u16 writes each (write banks ~2-way, see w1addr swizzle)
    #pragma unroll
    for (int it = 0; it < 8; ++it) {
        const int i = it * 1024 + tid * 4;   // element index: k = i>>6, j0 = i&63
        const int k = i >> 6, j0 = i & 63;
        f32x4 v = *reinterpret_cast<const f32x4*>(W1 + i);
        #pragma unroll
        for (int q = 0; q < 4; ++q)
            w1l[w1addr(k, j0 + q)] = f2bf_bits(v[q]);
    }
    __syncthreads();

    if (blockIdx.x == 0) {   // pack small weights once (runs alongside other blocks)
        for (int i = tid; i < 32 * 64; i += 256) {
            int j = i / 64, k = i % 64;
            w2t[i] = f2bf_bits(W2[k * 32 + j]);
        }
        for (int i = tid; i < 16 * 32; i += 256) {
            int j = i / 32, k = i % 32;
            w3t[i] = f2bf_bits(W3[k * 16 + j]);
        }
    }

    // A-frags via 16 ds_read_b128: lane holds W1^T[j=c*16+lr][k=s*32+lg*8 .. +7]
    s16x8 w1f[4][4];
    #pragma unroll
    for (int s = 0; s < 4; ++s)
        #pragma unroll
        for (int c = 0; c < 4; ++c)
            w1f[s][c] = *reinterpret_cast<const s16x8*>(
                &w1l[w1addr(s * 32 + lg * 8, c * 16 + lr)]);

    f32x4 b1q[4];
    #pragma unroll
    for (int c = 0; c < 4; ++c)
        b1q[c] = *reinterpret_cast<const f32x4*>(b1 + c * 16 + lg * 4);

    const int tile = blockIdx.x * 4 + wid;   // 1 node-tile per wave
    if (tile >= NODE_TILES) return;

    const int row = tile * 16 + lr;
    const float* p = nf + (long)row * 64;
    s16x8 nfr[2];
    #pragma unroll
    for (int s = 0; s < 2; ++s) {
        f32x4 a = *reinterpret_cast<const f32x4*>(p + s * 32 + lg * 8);
        f32x4 b = *reinterpret_cast<const f32x4*>(p + s * 32 + lg * 8 + 4);
        nfr[s] = cvt8(a, b);
    }
    f32x4 a4[4], b4[4];
    #pragma unroll
    for (int c = 0; c < 4; ++c) { a4[c] = (f32x4){0,0,0,0}; b4[c] = (f32x4){0,0,0,0}; }
    #pragma unroll
    for (int s = 0; s < 2; ++s)
        #pragma unroll
        for (int c = 0; c < 4; ++c) {
            a4[c] = __builtin_amdgcn_mfma_f32_16x16x32_bf16(w1f[s][c],     nfr[s], a4[c], 0, 0, 0);
            b4[c] = __builtin_amdgcn_mfma_f32_16x16x32_bf16(w1f[s + 2][c], nfr[s], b4[c], 0, 0, 0);
        }
    // D: lane holds feat j=c*16+lg*4+r of node=row; b1 folded into At
    #pragma unroll
    for (int c = 0; c < 4; ++c) {
        u32x2 pa, pb;
        pa[0] = pkbf(a4[c][0] + b1q[c][0], a4[c][1] + b1q[c][1]);
        pa[1] = pkbf(a4[c][2] + b1q[c][2], a4[c][3] + b1q[c][3]);
        pb[0] = pkbf(b4[c][0], b4[c][1]);
        pb[1] = pkbf(b4[c][2], b4[c][3]);
        *reinterpret_cast<u32x2*>(At + (long)row * 64 + c * 16 + lg * 4) = pa;
        *reinterpret_cast<u32x2*>(Bt + (long)row * 64 + c * 16 + lg * 4) = pb;
    }
}

__device__ __forceinline__ void gatherT(const unsigned short* At, const unsigned short* Bt,
                                        int si, int di, int lg, s16x8 g[4]) {
    const unsigned short* pa = At + (size_t)si * 64 + lg * 8;
    const unsigned short* pb = Bt + (size_t)di * 64 + lg * 8;
    g[0] = *reinterpret_cast<const s16x8*>(pa);
    g[1] = *reinterpret_cast<const s16x8*>(pa + 32);
    g[2] = *reinterpret_cast<const s16x8*>(pb);
    g[3] = *reinterpret_cast<const s16x8*>(pb + 32);
}

__device__ __forceinline__ void compute_tile(
    int tile, const s16x8 cur[4], f32x2 s2,
    const f32x2 c0p[2][4], const f32x2 c1p[2][4],
    const s16x8 w2f[2][2], s16x8 w3f,
    const f32x4 b2v[2], f32x4 b3v,
    unsigned short* h2w, int lg, int lr, float* __restrict__ out) {

    const f32x2 sp0v = {s2[0], s2[0]}, sp1v = {s2[1], s2[1]};

    s16x8 bfr[2];
    #pragma unroll
    for (int jb = 0; jb < 2; ++jb) {
        u32x4 au = __builtin_bit_cast(u32x4, cur[jb]);
        u32x4 bu = __builtin_bit_cast(u32x4, cur[2 + jb]);
        u32x4 pk4;
        #pragma unroll
        for (int q = 0; q < 4; ++q) {
            f32x2 av = {__builtin_bit_cast(float, au[q] << 16),
                        __builtin_bit_cast(float, au[q] & 0xFFFF0000u)};
            f32x2 bv = {__builtin_bit_cast(float, bu[q] << 16),
                        __builtin_bit_cast(float, bu[q] & 0xFFFF0000u)};
            f32x2 h = av + bv;
            h = sp1v * c1p[jb][q] + h;
            h = sp0v * c0p[jb][q] + h;
            pk4[q] = pkbf(fmaxf(h[0], 0.f), fmaxf(h[1], 0.f));
        }
        bfr[jb] = __builtin_bit_cast(s16x8, pk4);
    }

    f32x4 acc2[2];
    #pragma unroll
    for (int c = 0; c < 2; ++c) acc2[c] = (f32x4){0, 0, 0, 0};
    #pragma unroll
    for (int s = 0; s < 2; ++s)
        #pragma unroll
        for (int c = 0; c < 2; ++c)
            acc2[c] = __builtin_amdgcn_mfma_f32_16x16x32_bf16(w2f[s][c], bfr[s], acc2[c], 0, 0, 0);

    #pragma unroll
    for (int c = 0; c < 2; ++c) {
        u32x2 p;
        p[0] = pkbf(fmaxf(acc2[c][0] + b2v[c][0], 0.f), fmaxf(acc2[c][1] + b2v[c][1], 0.f));
        p[1] = pkbf(fmaxf(acc2[c][2] + b2v[c][2], 0.f), fmaxf(acc2[c][3] + b2v[c][3], 0.f));
        *reinterpret_cast<u32x2*>(h2w + c * 16 + lg * 4) = p;
    }

    s16x8 bf3 = *reinterpret_cast<const s16x8*>(h2w + lg * 8);
    f32x4 acc3 = (f32x4){0, 0, 0, 0};
    acc3 = __builtin_amdgcn_mfma_f32_16x16x32_bf16(w3f, bf3, acc3, 0, 0, 0);

    f32x4 o;
    #pragma unroll
    for (int r = 0; r < 4; ++r) o[r] = acc3[r] + b3v[r];
    __builtin_nontemporal_store(o,
        reinterpret_cast<f32x4*>(out + (long)(tile * 16 + lr) * 16 + lg * 4));
}

// ---- edge kernel: TPW=5, full idx prologue, depth-2 gather pipeline ----
__global__ __launch_bounds__(256) void edge_mlp_tab(
    const int* __restrict__ ei, const float* __restrict__ sp,
    const float* __restrict__ W1, const float* __restrict__ b2,
    const float* __restrict__ b3, const unsigned short* __restrict__ wsw,
    float* __restrict__ out) {

    const unsigned short* w2t = wsw + 10240;
    const unsigned short* w3t = wsw + 12288;
    const unsigned short* At  = wsw + TAB_OFF;
    const unsigned short* Bt  = At + (size_t)NN * 64;

    __shared__ unsigned short h2s[4 * 16 * 40];   // 5120 B, per-wave regions

    const int tid = threadIdx.x, wid = tid >> 6, lane = tid & 63;
    const int lr = lane & 15, lg = lane >> 4;

    const int tile0 = (blockIdx.x * 4 + wid) * TPW;

    s16x8 w2f[2][2], w3f;
    #pragma unroll
    for (int s = 0; s < 2; ++s)
        #pragma unroll
        for (int c = 0; c < 2; ++c)
            w2f[s][c] = *reinterpret_cast<const s16x8*>(w2t + (c * 16 + lr) * 64 + s * 32 + lg * 8);
    w3f = *reinterpret_cast<const s16x8*>(w3t + lr * 32 + lg * 8);

    f32x4 b2v[2];
    #pragma unroll
    for (int c = 0; c < 2; ++c) b2v[c] = *reinterpret_cast<const f32x4*>(b2 + c * 16 + lg * 4);
    const f32x4 b3v = *reinterpret_cast<const f32x4*>(b3 + lg * 4);

    // spatial-row consts as f32x2 pairs (feats j = jb*32 + lg*8 + 2q, 2q+1)
    f32x2 c0p[2][4], c1p[2][4];
    #pragma unroll
    for (int jb = 0; jb < 2; ++jb) {
        const int j0 = jb * 32 + lg * 8;
        f32x4 x0 = *reinterpret_cast<const f32x4*>(W1 + 128 * 64 + j0);
        f32x4 x1 = *reinterpret_cast<const f32x4*>(W1 + 128 * 64 + j0 + 4);
        f32x4 y0 = *reinterpret_cast<const f32x4*>(W1 + 129 * 64 + j0);
        f32x4 y1 = *reinterpret_cast<const f32x4*>(W1 + 129 * 64 + j0 + 4);
        c0p[jb][0] = (f32x2){x0[0], x0[1]}; c0p[jb][1] = (f32x2){x0[2], x0[3]};
        c0p[jb][2] = (f32x2){x1[0], x1[1]}; c0p[jb][3] = (f32x2){x1[2], x1[3]};
        c1p[jb][0] = (f32x2){y0[0], y0[1]}; c1p[jb][1] = (f32x2){y0[2], y0[3]};
        c1p[jb][2] = (f32x2){y1[0], y1[1]}; c1p[jb][3] = (f32x2){y1[2], y1[3]};
    }

    unsigned short* h2w = h2s + wid * (16 * 40) + lr * 40;

    // prologue: all TPW tiles' indices + spatial at once (batch latency)
    int si[TPW], di[TPW];
    f32x2 spv[TPW];
    #pragma unroll
    for (int t = 0; t < TPW; ++t) {
        const size_t e = (size_t)(tile0 + t) * 16 + lr;
        si[t] = ei[e];
        di[t] = ei[NE + e];
        spv[t] = *reinterpret_cast<const f32x2*>(sp + 2 * e);
    }

    // depth-2 pipeline, 3 named buffers (no runtime indexing)
    s16x8 gA[4], gB[4], gC[4];
    gatherT(At, Bt, si[0], di[0], lg, gA);
    gatherT(At, Bt, si[1], di[1], lg, gB);

    gatherT(At, Bt, si[2], di[2], lg, gC);
    compute_tile(tile0 + 0, gA, spv[0], c0p, c1p, w2f, w3f, b2v, b3v, h2w, lg, lr, out);

    gatherT(At, Bt, si[3], di[3], lg, gA);
    compute_tile(tile0 + 1, gB, spv[1], c0p, c1p, w2f, w3f, b2v, b3v, h2w, lg, lr, out);

    gatherT(At, Bt, si[4], di[4], lg, gB);
    compute_tile(tile0 + 2, gC, spv[2], c0p, c1p, w2f, w3f, b2v, b3v, h2w, lg, lr, out);

    compute_tile(tile0 + 3, gA, spv[3], c0p, c1p, w2f, w3f, b2v, b3v, h2w, lg, lr, out);
    compute_tile(tile0 + 4, gB, spv[4], c0p, c1p, w2f, w3f, b2v, b3v, h2w, lg, lr, out);
}

// ---------------- small-ws fallback (R2 kernel, proven) ----------------
__global__ void prep(const float* __restrict__ W1, const float* __restrict__ W2,
                     const float* __restrict__ W3, const float* __restrict__ nf,
                     unsigned short* __restrict__ ws, int do_nf) {
    unsigned short* w1t = ws;
    unsigned short* w2t = ws + 10240;
    unsigned short* w3t = ws + 12288;
    int t = blockIdx.x * blockDim.x + threadIdx.x;
    int stride = gridDim.x * blockDim.x;
    for (int i = t; i < 64 * 160; i += stride) {
        int j = i / 160, k = i % 160;
        w1t[i] = f2bf_bits(k < 130 ? W1[k * 64 + j] : 0.0f);
    }
    for (int i = t; i < 32 * 64; i += stride) {
        int j = i / 64, k = i % 64;
        w2t[i] = f2bf_bits(W2[k * 32 + j]);
    }
    for (int i = t; i < 16 * 32; i += stride) {
        int j = i / 32, k = i % 32;
        w3t[i] = f2bf_bits(W3[k * 16 + j]);
    }
    if (do_nf) {
        unsigned short* nfb = ws + TAB_OFF;
        for (int i = t; i < NN * 8; i += stride) {
            f32x4 a = *reinterpret_cast<const f32x4*>(nf + (long)i * 8);
            f32x4 b = *reinterpret_cast<const f32x4*>(nf + (long)i * 8 + 4);
            *reinterpret_cast<s16x8*>(nfb + (long)i * 8) = cvt8(a, b);
        }
    }
}

template <bool BF16NF>
__device__ __forceinline__ void gather4(const unsigned short* nfb, const float* nf,
                                        int si, int di, int lg, s16x8 g[4]) {
    if (BF16NF) {
        #pragma unroll
        for (int s = 0; s < 4; ++s) {
            const int row = (s < 2) ? si : di;
            g[s] = *reinterpret_cast<const s16x8*>(nfb + (long)row * 64 + (s & 1) * 32 + lg * 8);
        }
    } else {
        #pragma unroll
        for (int s = 0; s < 4; ++s) {
            const float* p = nf + (long)((s < 2) ? si : di) * 64 + (s & 1) * 32 + lg * 8;
            f32x4 a = *reinterpret_cast<const f32x4*>(p);
            f32x4 b = *reinterpret_cast<const f32x4*>(p + 4);
            g[s] = cvt8(a, b);
        }
    }
}

template <bool BF16NF>
__global__ __launch_bounds__(256) void edge_mlp_fb(
    const float* __restrict__ nf, const int* __restrict__ ei,
    const float* __restrict__ sp, const float* __restrict__ b1,
    const float* __restrict__ b2, const float* __restrict__ b3,
    const unsigned short* __restrict__ wsw, float* __restrict__ out) {

    const unsigned short* w1t = wsw;
    const unsigned short* w2t = wsw + 10240;
    const unsigned short* w3t = wsw + 12288;
    const unsigned short* nfb = wsw + TAB_OFF;

    __shared__ float h1s[4][16][68];
    __shared__ float h2s[4][16][36];

    const int tid = threadIdx.x, wid = tid >> 6, lane = tid & 63;
    const int lr = lane & 15, lg = lane >> 4;

    s16x8 w1f[5][4], w2f[2][2], w3f;
    #pragma unroll
    for (int s = 0; s < 5; ++s)
        #pragma unroll
        for (int c = 0; c < 4; ++c)
            w1f[s][c] = *reinterpret_cast<const s16x8*>(w1t + (c * 16 + lr) * 160 + s * 32 + lg * 8);
    #pragma unroll
    for (int s = 0; s < 2; ++s)
        #pragma unroll
        for (int c = 0; c < 2; ++c)
            w2f[s][c] = *reinterpret_cast<const s16x8*>(w2t + (c * 16 + lr) * 64 + s * 32 + lg * 8);
    w3f = *reinterpret_cast<const s16x8*>(w3t + lr * 32 + lg * 8);

    float bias1[4], bias2[2], bias3;
    #pragma unroll
    for (int c = 0; c < 4; ++c) bias1[c] = b1[c * 16 + lr];
    #pragma unroll
    for (int c = 0; c < 2; ++c) bias2[c] = b2[c * 16 + lr];
    bias3 = b3[lr];

    const int tile0 = (blockIdx.x * 4 + wid) * 4;
    int si[4], di[4];
    f32x2 spv[4];
    #pragma unroll
    for (int t = 0; t < 4; ++t) {
        const int e = (tile0 + t) * 16 + lr;
        si[t] = ei[e];
        di[t] = ei[NE + e];
        spv[t] = *reinterpret_cast<const f32x2*>(sp + 2 * (size_t)e);
    }

    s16x8 cur[4], nxt[4];
    gather4<BF16NF>(nfb, nf, si[0], di[0], lg, cur);

    #pragma unroll
    for (int tt = 0; tt < 4; ++tt) {
        if (tt + 1 < 4)
            gather4<BF16NF>(nfb, nf, si[tt + 1], di[tt + 1], lg, nxt);

        const int ebase = (tile0 + tt) * 16;

        f32x4 acc1[4];
        #pragma unroll
        for (int c = 0; c < 4; ++c) acc1[c] = (f32x4){0, 0, 0, 0};
        #pragma unroll
        for (int s = 0; s < 4; ++s)
            #pragma unroll
            for (int c = 0; c < 4; ++c)
                acc1[c] = __builtin_amdgcn_mfma_f32_16x16x32_bf16(cur[s], w1f[s][c], acc1[c], 0, 0, 0);
        {
            bf16x8 z;
            #pragma unroll
            for (int j = 0; j < 8; ++j) z[j] = (__bf16)0.0f;
            if (lg == 0) { z[0] = (__bf16)spv[tt][0]; z[1] = (__bf16)spv[tt][1]; }
            s16x8 af = __builtin_bit_cast(s16x8, z);
            #pragma unroll
            for (int c = 0; c < 4; ++c)
                acc1[c] = __builtin_amdgcn_mfma_f32_16x16x32_bf16(af, w1f[4][c], acc1[c], 0, 0, 0);
        }
        #pragma unroll
        for (int c = 0; c < 4; ++c)
            #pragma unroll
            for (int r = 0; r < 4; ++r)
                h1s[wid][lg * 4 + r][c * 16 + lr] = fmaxf(acc1[c][r] + bias1[c], 0.0f);

        f32x4 acc2[2];
        #pragma unroll
        for (int c = 0; c < 2; ++c) acc2[c] = (f32x4){0, 0, 0, 0};
        #pragma unroll
        for (int s = 0; s < 2; ++s) {
            f32x4 a = *reinterpret_cast<const f32x4*>(&h1s[wid][lr][s * 32 + lg * 8]);
            f32x4 b = *reinterpret_cast<const f32x4*>(&h1s[wid][lr][s * 32 + lg * 8 + 4]);
            s16x8 af = cvt8(a, b);
            #pragma unroll
            for (int c = 0; c < 2; ++c)
                acc2[c] = __builtin_amdgcn_mfma_f32_16x16x32_bf16(af, w2f[s][c], acc2[c], 0, 0, 0);
        }
        #pragma unroll
        for (int c = 0; c < 2; ++c)
            #pragma unroll
            for (int r = 0; r < 4; ++r)
                h2s[wid][lg * 4 + r][c * 16 + lr] = fmaxf(acc2[c][r] + bias2[c], 0.0f);

        f32x4 a3 = *reinterpret_cast<const f32x4*>(&h2s[wid][lr][lg * 8]);
        f32x4 b3x = *reinterpret_cast<const f32x4*>(&h2s[wid][lr][lg * 8 + 4]);
        s16x8 af3 = cvt8(a3, b3x);
        f32x4 acc3 = (f32x4){0, 0, 0, 0};
        acc3 = __builtin_amdgcn_mfma_f32_16x16x32_bf16(af3, w3f, acc3, 0, 0, 0);
        #pragma unroll
        for (int r = 0; r < 4; ++r)
            out[(long)(ebase + lg * 4 + r) * 16 + lr] = acc3[r] + bias3;

        #pragma unroll
        for (int s = 0; s < 4; ++s) cur[s] = nxt[s];
    }
}

extern "C" void kernel_launch(void* const* d_in, const int* in_sizes, int n_in,
                              void* d_out, int out_size, void* d_ws, size_t ws_size,
                              hipStream_t stream) {
    const float* nf = (const float*)d_in[0];
    const int*   ei = (const int*)d_in[1];
    const float* sp = (const float*)d_in[2];
    const float* W1 = (const float*)d_in[3];
    const float* b1 = (const float*)d_in[4];
    const float* W2 = (const float*)d_in[5];
    const float* b2 = (const float*)d_in[6];
    const float* W3 = (const float*)d_in[7];
    const float* b3 = (const float*)d_in[8];
    float* out = (float*)d_out;
    unsigned short* wsw = (unsigned short*)d_ws;

    const bool tab  = (ws_size >= WS_TAB);
    const bool bnfb = (!tab && ws_size >= WS_NFB);

    if (tab) {
        const int pblocks = (NODE_TILES + 3) / 4;   // 782, 1 tile/wave
        hipLaunchKernelGGL(node_prep_all, dim3(pblocks), dim3(256), 0, stream,
                           nf, W1, b1, W2, W3, wsw);
        const int blocks = NTILES / (TPW * 4);      // 2500
        hipLaunchKernelGGL(edge_mlp_tab, dim3(blocks), dim3(256), 0, stream,
                           ei, sp, W1, b2, b3, wsw, out);
    } else {
        hipLaunchKernelGGL(prep, dim3(64), dim3(256), 0, stream,
                           W1, W2, W3, nf, wsw, bnfb ? 1 : 0);
        const int blocks = NTILES / 4 / 4;   // 3125
        if (bnfb)
            hipLaunchKernelGGL(edge_mlp_fb<true>, dim3(blocks), dim3(256), 0, stream,
                               nf, ei, sp, b1, b2, b3, wsw, out);
        else
            hipLaunchKernelGGL(edge_mlp_fb<false>, dim3(blocks), dim3(256), 0, stream,
                               nf, ei, sp, b1, b2, b3, wsw, out);
    }
}

// Round 11
// 56.981 us; speedup vs baseline: 3.1406x; 1.0017x over previous
//
#include <hip/hip_runtime.h>
#include <hip/hip_bf16.h>
#include <hip/hip_cooperative_groups.h>

namespace cg = cooperative_groups;

#define NE 800000   // edges
#define NN 50000    // nodes
#define TPW 5       // tiles/wave, fallback edge kernel (2500 blocks)
#define NTILES (NE / 16)       // 50000
#define NODE_TILES (NN / 16)   // 3125
#define W1STR 136              // LDS row stride (shorts), 272B = 17*16B

// fused coop kernel geometry: 2048 blocks x 4 waves = 8192 waves
#define FBLOCKS 2048
#define FWAVES  (FBLOCKS * 4)
#define FTPW    6
#define FTAIL   (NTILES - FWAVES * FTPW)   // 848 waves take a 7th tile

typedef __attribute__((ext_vector_type(8))) short        s16x8;
typedef __attribute__((ext_vector_type(8))) __bf16       bf16x8;
typedef __attribute__((ext_vector_type(4))) float        f32x4;
typedef __attribute__((ext_vector_type(2))) float        f32x2;
typedef __attribute__((ext_vector_type(4))) unsigned int u32x4;
typedef __attribute__((ext_vector_type(2))) unsigned int u32x2;

// ws layout (unsigned short elems):
//   [0)      w1t region (fallback weight packs)
//   [10240)  w2t [32][64]
//   [12288)  w3t [16][32]
//   [16384)  At [NN][64] bf16 (nf @ W1[0:64] + b1); then Bt [NN][64]
#define TAB_OFF 16384
#define WS_TAB ((size_t)(TAB_OFF + 2ull * NN * 64) * 2)
#define WS_NFB ((size_t)(TAB_OFF + 1ull * NN * 64) * 2)

__device__ __forceinline__ unsigned short f2bf_bits(float f) {
    __bf16 b = (__bf16)f;
    return __builtin_bit_cast(unsigned short, b);
}

__device__ __forceinline__ unsigned int pkbf(float a, float b) {
    return (unsigned int)f2bf_bits(a) | ((unsigned int)f2bf_bits(b) << 16);
}

__device__ __forceinline__ s16x8 cvt8(f32x4 a, f32x4 b) {
    bf16x8 r;
    r[0] = (__bf16)a[0]; r[1] = (__bf16)a[1]; r[2] = (__bf16)a[2]; r[3] = (__bf16)a[3];
    r[4] = (__bf16)b[0]; r[5] = (__bf16)b[1]; r[6] = (__bf16)b[2]; r[7] = (__bf16)b[3];
    return __builtin_bit_cast(s16x8, r);
}

// swizzled LDS address for W1^T element (k, j)
__device__ __forceinline__ int w1addr(int k, int j) {
    return j * W1STR + (((k >> 3) ^ ((j >> 2) & 15)) << 3) + (k & 7);
}

__device__ __forceinline__ void gatherT(const unsigned short* At, const unsigned short* Bt,
                                        int si, int di, int lg, s16x8 g[4]) {
    const unsigned short* pa = At + (size_t)si * 64 + lg * 8;
    const unsigned short* pb = Bt + (size_t)di * 64 + lg * 8;
    g[0] = *reinterpret_cast<const s16x8*>(pa);
    g[1] = *reinterpret_cast<const s16x8*>(pa + 32);
    g[2] = *reinterpret_cast<const s16x8*>(pb);
    g[3] = *reinterpret_cast<const s16x8*>(pb + 32);
}

__device__ __forceinline__ void compute_tile(
    int tile, const s16x8 cur[4], f32x2 s2,
    const f32x2 c0p[2][4], const f32x2 c1p[2][4],
    const s16x8 w2f[2][2], s16x8 w3f,
    const f32x4 b2v[2], f32x4 b3v,
    unsigned short* h2w, int lg, int lr, float* __restrict__ out) {

    const f32x2 sp0v = {s2[0], s2[0]}, sp1v = {s2[1], s2[1]};

    s16x8 bfr[2];
    #pragma unroll
    for (int jb = 0; jb < 2; ++jb) {
        u32x4 au = __builtin_bit_cast(u32x4, cur[jb]);
        u32x4 bu = __builtin_bit_cast(u32x4, cur[2 + jb]);
        u32x4 pk4;
        #pragma unroll
        for (int q = 0; q < 4; ++q) {
            f32x2 av = {__builtin_bit_cast(float, au[q] << 16),
                        __builtin_bit_cast(float, au[q] & 0xFFFF0000u)};
            f32x2 bv = {__builtin_bit_cast(float, bu[q] << 16),
                        __builtin_bit_cast(float, bu[q] & 0xFFFF0000u)};
            f32x2 h = av + bv;
            h = sp1v * c1p[jb][q] + h;
            h = sp0v * c0p[jb][q] + h;
            pk4[q] = pkbf(fmaxf(h[0], 0.f), fmaxf(h[1], 0.f));
        }
        bfr[jb] = __builtin_bit_cast(s16x8, pk4);
    }

    f32x4 acc2[2];
    #pragma unroll
    for (int c = 0; c < 2; ++c) acc2[c] = (f32x4){0, 0, 0, 0};
    #pragma unroll
    for (int s = 0; s < 2; ++s)
        #pragma unroll
        for (int c = 0; c < 2; ++c)
            acc2[c] = __builtin_amdgcn_mfma_f32_16x16x32_bf16(w2f[s][c], bfr[s], acc2[c], 0, 0, 0);

    #pragma unroll
    for (int c = 0; c < 2; ++c) {
        u32x2 p;
        p[0] = pkbf(fmaxf(acc2[c][0] + b2v[c][0], 0.f), fmaxf(acc2[c][1] + b2v[c][1], 0.f));
        p[1] = pkbf(fmaxf(acc2[c][2] + b2v[c][2], 0.f), fmaxf(acc2[c][3] + b2v[c][3], 0.f));
        *reinterpret_cast<u32x2*>(h2w + c * 16 + lg * 4) = p;
    }

    s16x8 bf3 = *reinterpret_cast<const s16x8*>(h2w + lg * 8);
    f32x4 acc3 = (f32x4){0, 0, 0, 0};
    acc3 = __builtin_amdgcn_mfma_f32_16x16x32_bf16(w3f, bf3, acc3, 0, 0, 0);

    f32x4 o;
    #pragma unroll
    for (int r = 0; r < 4; ++r) o[r] = acc3[r] + b3v[r];
    __builtin_nontemporal_store(o,
        reinterpret_cast<f32x4*>(out + (long)(tile * 16 + lr) * 16 + lg * 4));
}

// ============ fused cooperative kernel: R10 prep body + grid.sync + R10 edge body ============
__global__ __launch_bounds__(256, 8) void fused_all(
    const float* __restrict__ nf, const int* __restrict__ ei,
    const float* __restrict__ sp, const float* __restrict__ W1,
    const float* __restrict__ b1, const float* __restrict__ W2,
    const float* __restrict__ b2, const float* __restrict__ W3,
    const float* __restrict__ b3, unsigned short* __restrict__ ws,
    float* __restrict__ out) {

    unsigned short* w2t = ws + 10240;
    unsigned short* w3t = ws + 12288;
    unsigned short* At  = ws + TAB_OFF;
    unsigned short* Bt  = At + (size_t)NN * 64;

    // phase A: W1 staging buffer; phase B: reused as h2 redistribute buffer
    __shared__ unsigned short smem[64 * W1STR];   // 17408 B

    const int tid = threadIdx.x, wid = tid >> 6, lane = tid & 63;
    const int lr = lane & 15, lg = lane >> 4;
    const int gw = blockIdx.x * 4 + wid;

    // ---------------- phase A (only first 782 blocks do work) ----------------
    if (blockIdx.x < (NODE_TILES + 3) / 4) {
        #pragma unroll
        for (int it = 0; it < 8; ++it) {
            const int i = it * 1024 + tid * 4;
            const int k = i >> 6, j0 = i & 63;
            f32x4 v = *reinterpret_cast<const f32x4*>(W1 + i);
            #pragma unroll
            for (int q = 0; q < 4; ++q)
                smem[w1addr(k, j0 + q)] = f2bf_bits(v[q]);
        }
        __syncthreads();

        if (blockIdx.x == 0) {
            for (int i = tid; i < 32 * 64; i += 256) {
                int j = i / 64, k = i % 64;
                w2t[i] = f2bf_bits(W2[k * 32 + j]);
            }
            for (int i = tid; i < 16 * 32; i += 256) {
                int j = i / 32, k = i % 32;
                w3t[i] = f2bf_bits(W3[k * 16 + j]);
            }
        }

        s16x8 w1f[4][4];
        #pragma unroll
        for (int s = 0; s < 4; ++s)
            #pragma unroll
            for (int c = 0; c < 4; ++c)
                w1f[s][c] = *reinterpret_cast<const s16x8*>(
                    &smem[w1addr(s * 32 + lg * 8, c * 16 + lr)]);

        if (gw < NODE_TILES) {
            f32x4 b1q[4];
            #pragma unroll
            for (int c = 0; c < 4; ++c)
                b1q[c] = *reinterpret_cast<const f32x4*>(b1 + c * 16 + lg * 4);

            const int row = gw * 16 + lr;
            const float* p = nf + (long)row * 64;
            s16x8 nfr[2];
            #pragma unroll
            for (int s = 0; s < 2; ++s) {
                f32x4 a = *reinterpret_cast<const f32x4*>(p + s * 32 + lg * 8);
                f32x4 b = *reinterpret_cast<const f32x4*>(p + s * 32 + lg * 8 + 4);
                nfr[s] = cvt8(a, b);
            }
            f32x4 a4[4], b4[4];
            #pragma unroll
            for (int c = 0; c < 4; ++c) { a4[c] = (f32x4){0,0,0,0}; b4[c] = (f32x4){0,0,0,0}; }
            #pragma unroll
            for (int s = 0; s < 2; ++s)
                #pragma unroll
                for (int c = 0; c < 4; ++c) {
                    a4[c] = __builtin_amdgcn_mfma_f32_16x16x32_bf16(w1f[s][c],     nfr[s], a4[c], 0, 0, 0);
                    b4[c] = __builtin_amdgcn_mfma_f32_16x16x32_bf16(w1f[s + 2][c], nfr[s], b4[c], 0, 0, 0);
                }
            #pragma unroll
            for (int c = 0; c < 4; ++c) {
                u32x2 pa, pb;
                pa[0] = pkbf(a4[c][0] + b1q[c][0], a4[c][1] + b1q[c][1]);
                pa[1] = pkbf(a4[c][2] + b1q[c][2], a4[c][3] + b1q[c][3]);
                pb[0] = pkbf(b4[c][0], b4[c][1]);
                pb[1] = pkbf(b4[c][2], b4[c][3]);
                *reinterpret_cast<u32x2*>(At + (long)row * 64 + c * 16 + lg * 4) = pa;
                *reinterpret_cast<u32x2*>(Bt + (long)row * 64 + c * 16 + lg * 4) = pb;
            }
        }
    }

    __threadfence();
    cg::this_grid().sync();

    // ---------------- phase B: R10 edge body, static 6(+1)-tile assignment ----------------
    s16x8 w2f[2][2], w3f;
    #pragma unroll
    for (int s = 0; s < 2; ++s)
        #pragma unroll
        for (int c = 0; c < 2; ++c)
            w2f[s][c] = *reinterpret_cast<const s16x8*>(w2t + (c * 16 + lr) * 64 + s * 32 + lg * 8);
    w3f = *reinterpret_cast<const s16x8*>(w3t + lr * 32 + lg * 8);

    f32x4 b2v[2];
    #pragma unroll
    for (int c = 0; c < 2; ++c) b2v[c] = *reinterpret_cast<const f32x4*>(b2 + c * 16 + lg * 4);
    const f32x4 b3v = *reinterpret_cast<const f32x4*>(b3 + lg * 4);

    f32x2 c0p[2][4], c1p[2][4];
    #pragma unroll
    for (int jb = 0; jb < 2; ++jb) {
        const int j0 = jb * 32 + lg * 8;
        f32x4 x0 = *reinterpret_cast<const f32x4*>(W1 + 128 * 64 + j0);
        f32x4 x1 = *reinterpret_cast<const f32x4*>(W1 + 128 * 64 + j0 + 4);
        f32x4 y0 = *reinterpret_cast<const f32x4*>(W1 + 129 * 64 + j0);
        f32x4 y1 = *reinterpret_cast<const f32x4*>(W1 + 129 * 64 + j0 + 4);
        c0p[jb][0] = (f32x2){x0[0], x0[1]}; c0p[jb][1] = (f32x2){x0[2], x0[3]};
        c0p[jb][2] = (f32x2){x1[0], x1[1]}; c0p[jb][3] = (f32x2){x1[2], x1[3]};
        c1p[jb][0] = (f32x2){y0[0], y0[1]}; c1p[jb][1] = (f32x2){y0[2], y0[3]};
        c1p[jb][2] = (f32x2){y1[0], y1[1]}; c1p[jb][3] = (f32x2){y1[2], y1[3]};
    }

    unsigned short* h2w = smem + wid * (16 * 40) + lr * 40;

    const bool extra = (gw < FTAIL);
    const int tile0 = gw * FTPW + (extra ? gw : FTAIL);

    int si[FTPW], di[FTPW];
    f32x2 spv[FTPW];
    #pragma unroll
    for (int t = 0; t < FTPW; ++t) {
        const size_t e = (size_t)(tile0 + t) * 16 + lr;
        si[t] = ei[e];
        di[t] = ei[NE + e];
        spv[t] = *reinterpret_cast<const f32x2*>(sp + 2 * e);
    }

    s16x8 gA[4], gB[4], gC[4];
    gatherT(At, Bt, si[0], di[0], lg, gA);
    gatherT(At, Bt, si[1], di[1], lg, gB);

    gatherT(At, Bt, si[2], di[2], lg, gC);
    compute_tile(tile0 + 0, gA, spv[0], c0p, c1p, w2f, w3f, b2v, b3v, h2w, lg, lr, out);

    gatherT(At, Bt, si[3], di[3], lg, gA);
    compute_tile(tile0 + 1, gB, spv[1], c0p, c1p, w2f, w3f, b2v, b3v, h2w, lg, lr, out);

    gatherT(At, Bt, si[4], di[4], lg, gB);
    compute_tile(tile0 + 2, gC, spv[2], c0p, c1p, w2f, w3f, b2v, b3v, h2w, lg, lr, out);

    gatherT(At, Bt, si[5], di[5], lg, gC);
    compute_tile(tile0 + 3, gA, spv[3], c0p, c1p, w2f, w3f, b2v, b3v, h2w, lg, lr, out);

    compute_tile(tile0 + 4, gB, spv[4], c0p, c1p, w2f, w3f, b2v, b3v, h2w, lg, lr, out);
    compute_tile(tile0 + 5, gC, spv[5], c0p, c1p, w2f, w3f, b2v, b3v, h2w, lg, lr, out);

    if (extra) {   // 7th tile for waves 0..FTAIL-1 (~10% of waves, tail-latency only)
        const int t6 = tile0 + 6;
        const size_t e = (size_t)t6 * 16 + lr;
        const int s6 = ei[e], d6 = ei[NE + e];
        const f32x2 p6 = *reinterpret_cast<const f32x2*>(sp + 2 * e);
        gatherT(At, Bt, s6, d6, lg, gA);
        compute_tile(t6, gA, p6, c0p, c1p, w2f, w3f, b2v, b3v, h2w, lg, lr, out);
    }
}

// ================= fallback: proven R10 two-kernel tab path =================
__global__ __launch_bounds__(256) void node_prep_all(
    const float* __restrict__ nf, const float* __restrict__ W1,
    const float* __restrict__ b1, const float* __restrict__ W2,
    const float* __restrict__ W3, unsigned short* __restrict__ ws) {
    unsigned short* w2t = ws + 10240;
    unsigned short* w3t = ws + 12288;
    unsigned short* At  = ws + TAB_OFF;
    unsigned short* Bt  = At + (size_t)NN * 64;

    __shared__ unsigned short w1l[64 * W1STR];

    const int tid = threadIdx.x, wid = tid >> 6, lane = tid & 63;
    const int lr = lane & 15, lg = lane >> 4;

    #pragma unroll
    for (int it = 0; it < 8; ++it) {
        const int i = it * 1024 + tid * 4;
        const int k = i >> 6, j0 = i & 63;
        f32x4 v = *reinterpret_cast<const f32x4*>(W1 + i);
        #pragma unroll
        for (int q = 0; q < 4; ++q)
            w1l[w1addr(k, j0 + q)] = f2bf_bits(v[q]);
    }
    __syncthreads();

    if (blockIdx.x == 0) {
        for (int i = tid; i < 32 * 64; i += 256) {
            int j = i / 64, k = i % 64;
            w2t[i] = f2bf_bits(W2[k * 32 + j]);
        }
        for (int i = tid; i < 16 * 32; i += 256) {
            int j = i / 32, k = i % 32;
            w3t[i] = f2bf_bits(W3[k * 16 + j]);
        }
    }

    s16x8 w1f[4][4];
    #pragma unroll
    for (int s = 0; s < 4; ++s)
        #pragma unroll
        for (int c = 0; c < 4; ++c)
            w1f[s][c] = *reinterpret_cast<const s16x8*>(
                &w1l[w1addr(s * 32 + lg * 8, c * 16 + lr)]);

    f32x4 b1q[4];
    #pragma unroll
    for (int c = 0; c < 4; ++c)
        b1q[c] = *reinterpret_cast<const f32x4*>(b1 + c * 16 + lg * 4);

    const int tile = blockIdx.x * 4 + wid;
    if (tile >= NODE_TILES) return;

    const int row = tile * 16 + lr;
    const float* p = nf + (long)row * 64;
    s16x8 nfr[2];
    #pragma unroll
    for (int s = 0; s < 2; ++s) {
        f32x4 a = *reinterpret_cast<const f32x4*>(p + s * 32 + lg * 8);
        f32x4 b = *reinterpret_cast<const f32x4*>(p + s * 32 + lg * 8 + 4);
        nfr[s] = cvt8(a, b);
    }
    f32x4 a4[4], b4[4];
    #pragma unroll
    for (int c = 0; c < 4; ++c) { a4[c] = (f32x4){0,0,0,0}; b4[c] = (f32x4){0,0,0,0}; }
    #pragma unroll
    for (int s = 0; s < 2; ++s)
        #pragma unroll
        for (int c = 0; c < 4; ++c) {
            a4[c] = __builtin_amdgcn_mfma_f32_16x16x32_bf16(w1f[s][c],     nfr[s], a4[c], 0, 0, 0);
            b4[c] = __builtin_amdgcn_mfma_f32_16x16x32_bf16(w1f[s + 2][c], nfr[s], b4[c], 0, 0, 0);
        }
    #pragma unroll
    for (int c = 0; c < 4; ++c) {
        u32x2 pa, pb;
        pa[0] = pkbf(a4[c][0] + b1q[c][0], a4[c][1] + b1q[c][1]);
        pa[1] = pkbf(a4[c][2] + b1q[c][2], a4[c][3] + b1q[c][3]);
        pb[0] = pkbf(b4[c][0], b4[c][1]);
        pb[1] = pkbf(b4[c][2], b4[c][3]);
        *reinterpret_cast<u32x2*>(At + (long)row * 64 + c * 16 + lg * 4) = pa;
        *reinterpret_cast<u32x2*>(Bt + (long)row * 64 + c * 16 + lg * 4) = pb;
    }
}

__global__ __launch_bounds__(256) void edge_mlp_tab(
    const int* __restrict__ ei, const float* __restrict__ sp,
    const float* __restrict__ W1, const float* __restrict__ b2,
    const float* __restrict__ b3, const unsigned short* __restrict__ wsw,
    float* __restrict__ out) {

    const unsigned short* w2t = wsw + 10240;
    const unsigned short* w3t = wsw + 12288;
    const unsigned short* At  = wsw + TAB_OFF;
    const unsigned short* Bt  = At + (size_t)NN * 64;

    __shared__ unsigned short h2s[4 * 16 * 40];

    const int tid = threadIdx.x, wid = tid >> 6, lane = tid & 63;
    const int lr = lane & 15, lg = lane >> 4;

    const int tile0 = (blockIdx.x * 4 + wid) * TPW;

    s16x8 w2f[2][2], w3f;
    #pragma unroll
    for (int s = 0; s < 2; ++s)
        #pragma unroll
        for (int c = 0; c < 2; ++c)
            w2f[s][c] = *reinterpret_cast<const s16x8*>(w2t + (c * 16 + lr) * 64 + s * 32 + lg * 8);
    w3f = *reinterpret_cast<const s16x8*>(w3t + lr * 32 + lg * 8);

    f32x4 b2v[2];
    #pragma unroll
    for (int c = 0; c < 2; ++c) b2v[c] = *reinterpret_cast<const f32x4*>(b2 + c * 16 + lg * 4);
    const f32x4 b3v = *reinterpret_cast<const f32x4*>(b3 + lg * 4);

    f32x2 c0p[2][4], c1p[2][4];
    #pragma unroll
    for (int jb = 0; jb < 2; ++jb) {
        const int j0 = jb * 32 + lg * 8;
        f32x4 x0 = *reinterpret_cast<const f32x4*>(W1 + 128 * 64 + j0);
        f32x4 x1 = *reinterpret_cast<const f32x4*>(W1 + 128 * 64 + j0 + 4);
        f32x4 y0 = *reinterpret_cast<const f32x4*>(W1 + 129 * 64 + j0);
        f32x4 y1 = *reinterpret_cast<const f32x4*>(W1 + 129 * 64 + j0 + 4);
        c0p[jb][0] = (f32x2){x0[0], x0[1]}; c0p[jb][1] = (f32x2){x0[2], x0[3]};
        c0p[jb][2] = (f32x2){x1[0], x1[1]}; c0p[jb][3] = (f32x2){x1[2], x1[3]};
        c1p[jb][0] = (f32x2){y0[0], y0[1]}; c1p[jb][1] = (f32x2){y0[2], y0[3]};
        c1p[jb][2] = (f32x2){y1[0], y1[1]}; c1p[jb][3] = (f32x2){y1[2], y1[3]};
    }

    unsigned short* h2w = h2s + wid * (16 * 40) + lr * 40;

    int si[TPW], di[TPW];
    f32x2 spv[TPW];
    #pragma unroll
    for (int t = 0; t < TPW; ++t) {
        const size_t e = (size_t)(tile0 + t) * 16 + lr;
        si[t] = ei[e];
        di[t] = ei[NE + e];
        spv[t] = *reinterpret_cast<const f32x2*>(sp + 2 * e);
    }

    s16x8 gA[4], gB[4], gC[4];
    gatherT(At, Bt, si[0], di[0], lg, gA);
    gatherT(At, Bt, si[1], di[1], lg, gB);

    gatherT(At, Bt, si[2], di[2], lg, gC);
    compute_tile(tile0 + 0, gA, spv[0], c0p, c1p, w2f, w3f, b2v, b3v, h2w, lg, lr, out);

    gatherT(At, Bt, si[3], di[3], lg, gA);
    compute_tile(tile0 + 1, gB, spv[1], c0p, c1p, w2f, w3f, b2v, b3v, h2w, lg, lr, out);

    gatherT(At, Bt, si[4], di[4], lg, gB);
    compute_tile(tile0 + 2, gC, spv[2], c0p, c1p, w2f, w3f, b2v, b3v, h2w, lg, lr, out);

    compute_tile(tile0 + 3, gA, spv[3], c0p, c1p, w2f, w3f, b2v, b3v, h2w, lg, lr, out);
    compute_tile(tile0 + 4, gB, spv[4], c0p, c1p, w2f, w3f, b2v, b3v, h2w, lg, lr, out);
}

// ---------------- small-ws fallback (R2 kernel, proven) ----------------
__global__ void prep(const float* __restrict__ W1, const float* __restrict__ W2,
                     const float* __restrict__ W3, const float* __restrict__ nf,
                     unsigned short* __restrict__ ws, int do_nf) {
    unsigned short* w1t = ws;
    unsigned short* w2t = ws + 10240;
    unsigned short* w3t = ws + 12288;
    int t = blockIdx.x * blockDim.x + threadIdx.x;
    int stride = gridDim.x * blockDim.x;
    for (int i = t; i < 64 * 160; i += stride) {
        int j = i / 160, k = i % 160;
        w1t[i] = f2bf_bits(k < 130 ? W1[k * 64 + j] : 0.0f);
    }
    for (int i = t; i < 32 * 64; i += stride) {
        int j = i / 64, k = i % 64;
        w2t[i] = f2bf_bits(W2[k * 32 + j]);
    }
    for (int i = t; i < 16 * 32; i += stride) {
        int j = i / 32, k = i % 32;
        w3t[i] = f2bf_bits(W3[k * 16 + j]);
    }
    if (do_nf) {
        unsigned short* nfb = ws + TAB_OFF;
        for (int i = t; i < NN * 8; i += stride) {
            f32x4 a = *reinterpret_cast<const f32x4*>(nf + (long)i * 8);
            f32x4 b = *reinterpret_cast<const f32x4*>(nf + (long)i * 8 + 4);
            *reinterpret_cast<s16x8*>(nfb + (long)i * 8) = cvt8(a, b);
        }
    }
}

template <bool BF16NF>
__device__ __forceinline__ void gather4(const unsigned short* nfb, const float* nf,
                                        int si, int di, int lg, s16x8 g[4]) {
    if (BF16NF) {
        #pragma unroll
        for (int s = 0; s < 4; ++s) {
            const int row = (s < 2) ? si : di;
            g[s] = *reinterpret_cast<const s16x8*>(nfb + (long)row * 64 + (s & 1) * 32 + lg * 8);
        }
    } else {
        #pragma unroll
        for (int s = 0; s < 4; ++s) {
            const float* p = nf + (long)((s < 2) ? si : di) * 64 + (s & 1) * 32 + lg * 8;
            f32x4 a = *reinterpret_cast<const f32x4*>(p);
            f32x4 b = *reinterpret_cast<const f32x4*>(p + 4);
            g[s] = cvt8(a, b);
        }
    }
}

template <bool BF16NF>
__global__ __launch_bounds__(256) void edge_mlp_fb(
    const float* __restrict__ nf, const int* __restrict__ ei,
    const float* __restrict__ sp, const float* __restrict__ b1,
    const float* __restrict__ b2, const float* __restrict__ b3,
    const unsigned short* __restrict__ wsw, float* __restrict__ out) {

    const unsigned short* w1t = wsw;
    const unsigned short* w2t = wsw + 10240;
    const unsigned short* w3t = wsw + 12288;
    const unsigned short* nfb = wsw + TAB_OFF;

    __shared__ float h1s[4][16][68];
    __shared__ float h2s[4][16][36];

    const int tid = threadIdx.x, wid = tid >> 6, lane = tid & 63;
    const int lr = lane & 15, lg = lane >> 4;

    s16x8 w1f[5][4], w2f[2][2], w3f;
    #pragma unroll
    for (int s = 0; s < 5; ++s)
        #pragma unroll
        for (int c = 0; c < 4; ++c)
            w1f[s][c] = *reinterpret_cast<const s16x8*>(w1t + (c * 16 + lr) * 160 + s * 32 + lg * 8);
    #pragma unroll
    for (int s = 0; s < 2; ++s)
        #pragma unroll
        for (int c = 0; c < 2; ++c)
            w2f[s][c] = *reinterpret_cast<const s16x8*>(w2t + (c * 16 + lr) * 64 + s * 32 + lg * 8);
    w3f = *reinterpret_cast<const s16x8*>(w3t + lr * 32 + lg * 8);

    float bias1[4], bias2[2], bias3;
    #pragma unroll
    for (int c = 0; c < 4; ++c) bias1[c] = b1[c * 16 + lr];
    #pragma unroll
    for (int c = 0; c < 2; ++c) bias2[c] = b2[c * 16 + lr];
    bias3 = b3[lr];

    const int tile0 = (blockIdx.x * 4 + wid) * 4;
    int si[4], di[4];
    f32x2 spv[4];
    #pragma unroll
    for (int t = 0; t < 4; ++t) {
        const int e = (tile0 + t) * 16 + lr;
        si[t] = ei[e];
        di[t] = ei[NE + e];
        spv[t] = *reinterpret_cast<const f32x2*>(sp + 2 * (size_t)e);
    }

    s16x8 cur[4], nxt[4];
    gather4<BF16NF>(nfb, nf, si[0], di[0], lg, cur);

    #pragma unroll
    for (int tt = 0; tt < 4; ++tt) {
        if (tt + 1 < 4)
            gather4<BF16NF>(nfb, nf, si[tt + 1], di[tt + 1], lg, nxt);

        const int ebase = (tile0 + tt) * 16;

        f32x4 acc1[4];
        #pragma unroll
        for (int c = 0; c < 4; ++c) acc1[c] = (f32x4){0, 0, 0, 0};
        #pragma unroll
        for (int s = 0; s < 4; ++s)
            #pragma unroll
            for (int c = 0; c < 4; ++c)
                acc1[c] = __builtin_amdgcn_mfma_f32_16x16x32_bf16(cur[s], w1f[s][c], acc1[c], 0, 0, 0);
        {
            bf16x8 z;
            #pragma unroll
            for (int j = 0; j < 8; ++j) z[j] = (__bf16)0.0f;
            if (lg == 0) { z[0] = (__bf16)spv[tt][0]; z[1] = (__bf16)spv[tt][1]; }
            s16x8 af = __builtin_bit_cast(s16x8, z);
            #pragma unroll
            for (int c = 0; c < 4; ++c)
                acc1[c] = __builtin_amdgcn_mfma_f32_16x16x32_bf16(af, w1f[4][c], acc1[c], 0, 0, 0);
        }
        #pragma unroll
        for (int c = 0; c < 4; ++c)
            #pragma unroll
            for (int r = 0; r < 4; ++r)
                h1s[wid][lg * 4 + r][c * 16 + lr] = fmaxf(acc1[c][r] + bias1[c], 0.0f);

        f32x4 acc2[2];
        #pragma unroll
        for (int c = 0; c < 2; ++c) acc2[c] = (f32x4){0, 0, 0, 0};
        #pragma unroll
        for (int s = 0; s < 2; ++s) {
            f32x4 a = *reinterpret_cast<const f32x4*>(&h1s[wid][lr][s * 32 + lg * 8]);
            f32x4 b = *reinterpret_cast<const f32x4*>(&h1s[wid][lr][s * 32 + lg * 8 + 4]);
            s16x8 af = cvt8(a, b);
            #pragma unroll
            for (int c = 0; c < 2; ++c)
                acc2[c] = __builtin_amdgcn_mfma_f32_16x16x32_bf16(af, w2f[s][c], acc2[c], 0, 0, 0);
        }
        #pragma unroll
        for (int c = 0; c < 2; ++c)
            #pragma unroll
            for (int r = 0; r < 4; ++r)
                h2s[wid][lg * 4 + r][c * 16 + lr] = fmaxf(acc2[c][r] + bias2[c], 0.0f);

        f32x4 a3 = *reinterpret_cast<const f32x4*>(&h2s[wid][lr][lg * 8]);
        f32x4 b3x = *reinterpret_cast<const f32x4*>(&h2s[wid][lr][lg * 8 + 4]);
        s16x8 af3 = cvt8(a3, b3x);
        f32x4 acc3 = (f32x4){0, 0, 0, 0};
        acc3 = __builtin_amdgcn_mfma_f32_16x16x32_bf16(af3, w3f, acc3, 0, 0, 0);
        #pragma unroll
        for (int r = 0; r < 4; ++r)
            out[(long)(ebase + lg * 4 + r) * 16 + lr] = acc3[r] + bias3;

        #pragma unroll
        for (int s = 0; s < 4; ++s) cur[s] = nxt[s];
    }
}

extern "C" void kernel_launch(void* const* d_in, const int* in_sizes, int n_in,
                              void* d_out, int out_size, void* d_ws, size_t ws_size,
                              hipStream_t stream) {
    const float* nf = (const float*)d_in[0];
    const int*   ei = (const int*)d_in[1];
    const float* sp = (const float*)d_in[2];
    const float* W1 = (const float*)d_in[3];
    const float* b1 = (const float*)d_in[4];
    const float* W2 = (const float*)d_in[5];
    const float* b2 = (const float*)d_in[6];
    const float* W3 = (const float*)d_in[7];
    const float* b3 = (const float*)d_in[8];
    float* out = (float*)d_out;
    unsigned short* wsw = (unsigned short*)d_ws;

    const bool tab  = (ws_size >= WS_TAB);
    const bool bnfb = (!tab && ws_size >= WS_NFB);

    if (tab) {
        // single fused cooperative kernel if FBLOCKS can be co-resident
        bool done = false;
        int maxb = 0, ncu = 0;
        if (hipOccupancyMaxActiveBlocksPerMultiprocessor(
                &maxb, (const void*)fused_all, 256, 0) == hipSuccess &&
            hipDeviceGetAttribute(&ncu, hipDeviceAttributeMultiprocessorCount, 0)
                == hipSuccess && (long)maxb * ncu >= FBLOCKS) {
            void* args[] = {(void*)&nf, (void*)&ei, (void*)&sp, (void*)&W1,
                            (void*)&b1, (void*)&W2, (void*)&b2, (void*)&W3,
                            (void*)&b3, (void*)&wsw, (void*)&out};
            hipError_t le = hipLaunchCooperativeKernel(
                (const void*)fused_all, dim3(FBLOCKS), dim3(256), args, 0, stream);
            done = (le == hipSuccess);
        }
        if (!done) {   // proven R10 two-kernel path
            const int pblocks = (NODE_TILES + 3) / 4;   // 782
            hipLaunchKernelGGL(node_prep_all, dim3(pblocks), dim3(256), 0, stream,
                               nf, W1, b1, W2, W3, wsw);
            const int blocks = NTILES / (TPW * 4);      // 2500
            hipLaunchKernelGGL(edge_mlp_tab, dim3(blocks), dim3(256), 0, stream,
                               ei, sp, W1, b2, b3, wsw, out);
        }
    } else {
        hipLaunchKernelGGL(prep, dim3(64), dim3(256), 0, stream,
                           W1, W2, W3, nf, wsw, bnfb ? 1 : 0);
        const int blocks = NTILES / 4 / 4;   // 3125
        if (bnfb)
            hipLaunchKernelGGL(edge_mlp_fb<true>, dim3(blocks), dim3(256), 0, stream,
                               nf, ei, sp, b1, b2, b3, wsw, out);
        else
            hipLaunchKernelGGL(edge_mlp_fb<false>, dim3(blocks), dim3(256), 0, stream,
                               nf, ei, sp, b1, b2, b3, wsw, out);
    }
}